// Round 1
// baseline (1253.078 us; speedup 1.0000x reference)
//
#include <hip/hip_runtime.h>

#define NNODES 50000
#define NEDGES 800000
#define ETOT   (NNODES + NEDGES)   // 850000 edges incl. self-loops
#define NH     8
#define HID    64
#define D1     512                  // NH*HID
#define INC    512
#define OUTC   128
#define NEG    0.2f

// ---------------- CSR build ----------------
__global__ void count_deg(const int* __restrict__ ei, int* __restrict__ deg) {
    int i = blockIdx.x * 256 + threadIdx.x;
    if (i >= ETOT) return;
    int dst = (i < NEDGES) ? ei[NEDGES + i] : (i - NEDGES);
    atomicAdd(&deg[dst], 1);
}

__global__ void scan_deg(const int* __restrict__ deg, int* __restrict__ rs) {
    __shared__ int part[1024];
    const int n = NNODES;
    const int CH = (n + 1023) / 1024;   // 49
    int t = threadIdx.x;
    int lo = t * CH, hi = min(lo + CH, n);
    int s = 0;
    for (int i = lo; i < hi; ++i) s += deg[i];
    part[t] = s;
    __syncthreads();
    for (int off = 1; off < 1024; off <<= 1) {
        int v = (t >= off) ? part[t - off] : 0;
        __syncthreads();
        part[t] += v;
        __syncthreads();
    }
    int run = (t == 0) ? 0 : part[t - 1];
    for (int i = lo; i < hi; ++i) { rs[i] = run; run += deg[i]; }
    if (hi == n) rs[n] = run;   // total; threads with empty chunks write same value
}

__global__ void scatter_edges(const int* __restrict__ ei, int* __restrict__ cursor,
                              int* __restrict__ csr_src) {
    int i = blockIdx.x * 256 + threadIdx.x;
    if (i >= ETOT) return;
    int src, dst;
    if (i < NEDGES) { src = ei[i]; dst = ei[NEDGES + i]; }
    else            { src = dst = i - NEDGES; }
    int pos = atomicAdd(&cursor[dst], 1);
    csr_src[pos] = src;
}

// ---------------- fp32 tiled GEMM: C[M,N] = A[M,K] @ B[K,N] ----------------
template<int BM, int BN, int BK, int TM, int TN>
__global__ __launch_bounds__(256) void gemm_f32(const float* __restrict__ A,
                                                const float* __restrict__ B,
                                                float* __restrict__ C,
                                                int M, int N, int K) {
    constexpr int THREADS = (BM / TM) * (BN / TN);   // 256
    __shared__ float As[BK][BM];   // stored transposed: As[k][m]
    __shared__ float Bs[BK][BN];
    int tid = threadIdx.x;
    int tx = tid % (BN / TN);
    int ty = tid / (BN / TN);
    int m0 = blockIdx.x * BM;
    int n0 = blockIdx.y * BN;
    float acc[TM][TN] = {};
    constexpr int A_F4 = BM * BK / 4;
    constexpr int B_F4 = BK * BN / 4;
    for (int k0 = 0; k0 < K; k0 += BK) {
        for (int f = tid; f < A_F4; f += THREADS) {
            int r  = f / (BK / 4);
            int k4 = (f % (BK / 4)) * 4;
            float4 v = make_float4(0.f, 0.f, 0.f, 0.f);
            int row = m0 + r;
            if (row < M) v = *(const float4*)&A[(size_t)row * K + k0 + k4];
            As[k4 + 0][r] = v.x; As[k4 + 1][r] = v.y;
            As[k4 + 2][r] = v.z; As[k4 + 3][r] = v.w;
        }
        for (int f = tid; f < B_F4; f += THREADS) {
            int kk = f / (BN / 4);
            int c4 = (f % (BN / 4)) * 4;
            *(float4*)&Bs[kk][c4] = *(const float4*)&B[(size_t)(k0 + kk) * N + n0 + c4];
        }
        __syncthreads();
        #pragma unroll
        for (int k = 0; k < BK; ++k) {
            float a[TM], b[TN];
            #pragma unroll
            for (int i = 0; i < TM; i += 4) *(float4*)&a[i] = *(float4*)&As[k][ty * TM + i];
            #pragma unroll
            for (int j = 0; j < TN; j += 4) *(float4*)&b[j] = *(float4*)&Bs[k][tx * TN + j];
            #pragma unroll
            for (int i = 0; i < TM; ++i)
                #pragma unroll
                for (int j = 0; j < TN; ++j)
                    acc[i][j] += a[i] * b[j];
        }
        __syncthreads();
    }
    for (int i = 0; i < TM; ++i) {
        int row = m0 + ty * TM + i;
        if (row >= M) break;
        for (int j = 0; j < TN; j += 4) {
            float4 v = make_float4(acc[i][j], acc[i][j+1], acc[i][j+2], acc[i][j+3]);
            *(float4*)&C[(size_t)row * N + n0 + tx * TN + j] = v;
        }
    }
}

// ---------------- attention dot products ----------------
// layer 1: one wave per (node, head); lane = channel
__global__ void dots1(const float* __restrict__ h1, const float* __restrict__ a_src,
                      const float* __restrict__ a_dst,
                      float* __restrict__ esrc, float* __restrict__ edst) {
    int gw   = (blockIdx.x * blockDim.x + threadIdx.x) >> 6;
    int lane = threadIdx.x & 63;
    if (gw >= NNODES * NH) return;
    int h = gw & (NH - 1);
    float x = h1[(size_t)gw * HID + lane];   // gw*64 == n*512 + h*64
    float s = x * a_src[h * HID + lane];
    float d = x * a_dst[h * HID + lane];
    for (int off = 32; off; off >>= 1) {
        s += __shfl_down(s, off);
        d += __shfl_down(d, off);
    }
    if (lane == 0) { esrc[gw] = s; edst[gw] = d; }
}

// layer 2: one wave per node, 128 channels
__global__ void dots2(const float* __restrict__ h2, const float* __restrict__ a_src,
                      const float* __restrict__ a_dst,
                      float* __restrict__ esrc, float* __restrict__ edst) {
    int gw   = (blockIdx.x * blockDim.x + threadIdx.x) >> 6;
    int lane = threadIdx.x & 63;
    if (gw >= NNODES) return;
    float x0 = h2[(size_t)gw * OUTC + lane];
    float x1 = h2[(size_t)gw * OUTC + 64 + lane];
    float s = x0 * a_src[lane] + x1 * a_src[64 + lane];
    float d = x0 * a_dst[lane] + x1 * a_dst[64 + lane];
    for (int off = 32; off; off >>= 1) {
        s += __shfl_down(s, off);
        d += __shfl_down(d, off);
    }
    if (lane == 0) { esrc[gw] = s; edst[gw] = d; }
}

__device__ __forceinline__ float leaky(float v) { return v >= 0.f ? v : NEG * v; }
__device__ __forceinline__ unsigned fkey(float v) {
    unsigned u = __float_as_uint(v);
    return (u & 0x80000000u) ? ~u : (u | 0x80000000u);
}
__device__ __forceinline__ float funkey(unsigned k) {
    return __uint_as_float((k & 0x80000000u) ? (k & 0x7fffffffu) : ~k);
}

// ---------------- layer-1 aggregation: one block (256 thr) per dst node ----------------
__global__ __launch_bounds__(256) void attn1(const float* __restrict__ h1,
                                             const float* __restrict__ esrc,
                                             const float* __restrict__ edst,
                                             const int* __restrict__ rs,
                                             const int* __restrict__ csr_src,
                                             const float* __restrict__ b1,
                                             float* __restrict__ out1) {
    int n = blockIdx.x;
    int t = threadIdx.x;
    int beg = rs[n], deg = rs[n + 1] - beg;
    __shared__ unsigned mkey[NH];
    __shared__ float msh[NH], ssh[NH];
    if (t < NH) mkey[t] = 0u;
    __syncthreads();
    // pass A: per-head max
    for (int idx = t; idx < deg * NH; idx += 256) {
        int e = idx >> 3, h = idx & 7;
        int s = csr_src[beg + e];
        float v = leaky(esrc[s * NH + h] + edst[n * NH + h]);
        atomicMax(&mkey[h], fkey(v));
    }
    __syncthreads();
    if (t < NH) { msh[t] = funkey(mkey[t]); ssh[t] = 0.f; }
    __syncthreads();
    // pass B: per-head sum of exp
    for (int idx = t; idx < deg * NH; idx += 256) {
        int e = idx >> 3, h = idx & 7;
        int s = csr_src[beg + e];
        float v = leaky(esrc[s * NH + h] + edst[n * NH + h]);
        atomicAdd(&ssh[h], __expf(v - msh[h]));
    }
    __syncthreads();
    // pass C: weighted accumulate; thread owns channels t and t+256
    int c0 = t, c1 = t + 256;
    int h0 = c0 >> 6, h1i = c1 >> 6;
    float m0 = msh[h0], m1 = msh[h1i];
    float ed0 = edst[n * NH + h0], ed1 = edst[n * NH + h1i];
    float acc0 = 0.f, acc1 = 0.f;
    for (int e = 0; e < deg; ++e) {
        int s = csr_src[beg + e];
        float a0 = __expf(leaky(esrc[s * NH + h0] + ed0) - m0);
        float a1 = __expf(leaky(esrc[s * NH + h1i] + ed1) - m1);
        acc0 += a0 * h1[(size_t)s * D1 + c0];
        acc1 += a1 * h1[(size_t)s * D1 + c1];
    }
    float inv0 = 1.f / (ssh[h0] + 1e-16f);
    float inv1 = 1.f / (ssh[h1i] + 1e-16f);
    out1[(size_t)n * D1 + c0] = fmaxf(acc0 * inv0 + b1[c0], 0.f);
    out1[(size_t)n * D1 + c1] = fmaxf(acc1 * inv1 + b1[c1], 0.f);
}

// ---------------- layer-2 aggregation: one block (128 thr) per dst node ----------------
__global__ __launch_bounds__(128) void attn2(const float* __restrict__ h2,
                                             const float* __restrict__ esrc,
                                             const float* __restrict__ edst,
                                             const int* __restrict__ rs,
                                             const int* __restrict__ csr_src,
                                             const float* __restrict__ b2,
                                             float* __restrict__ out) {
    int n = blockIdx.x;
    int t = threadIdx.x;
    int beg = rs[n], deg = rs[n + 1] - beg;
    __shared__ unsigned mkey;
    __shared__ float msh, ssh;
    if (t == 0) mkey = 0u;
    __syncthreads();
    float edn = edst[n];
    for (int e = t; e < deg; e += 128) {
        int s = csr_src[beg + e];
        atomicMax(&mkey, fkey(leaky(esrc[s] + edn)));
    }
    __syncthreads();
    if (t == 0) { msh = funkey(mkey); ssh = 0.f; }
    __syncthreads();
    for (int e = t; e < deg; e += 128) {
        int s = csr_src[beg + e];
        atomicAdd(&ssh, __expf(leaky(esrc[s] + edn) - msh));
    }
    __syncthreads();
    float m = msh;
    float acc = 0.f;
    for (int e = 0; e < deg; ++e) {
        int s = csr_src[beg + e];
        float a = __expf(leaky(esrc[s] + edn) - m);
        acc += a * h2[(size_t)s * OUTC + t];
    }
    out[(size_t)n * OUTC + t] = acc / (ssh + 1e-16f) + b2[t];
}

// ---------------- launch ----------------
extern "C" void kernel_launch(void* const* d_in, const int* in_sizes, int n_in,
                              void* d_out, int out_size, void* d_ws, size_t ws_size,
                              hipStream_t stream) {
    const float* x   = (const float*)d_in[0];
    const int*   ei  = (const int*)  d_in[1];
    const float* W1  = (const float*)d_in[2];
    const float* b1  = (const float*)d_in[3];
    const float* as1 = (const float*)d_in[4];
    const float* ad1 = (const float*)d_in[5];
    const float* W2  = (const float*)d_in[6];
    const float* b2  = (const float*)d_in[7];
    const float* as2 = (const float*)d_in[8];
    const float* ad2 = (const float*)d_in[9];
    float* out = (float*)d_out;

    char* ws = (char*)d_ws;
    size_t off = 0;
    auto alloc = [&](size_t bytes) -> void* {
        void* p = ws + off;
        off = (off + bytes + 255) & ~(size_t)255;
        return p;
    };
    float* h1   = (float*)alloc((size_t)NNODES * D1 * 4);
    float* out1 = (float*)alloc((size_t)NNODES * D1 * 4);
    float* h2   = (float*)alloc((size_t)NNODES * OUTC * 4);
    float* es1  = (float*)alloc((size_t)NNODES * NH * 4);
    float* ed1  = (float*)alloc((size_t)NNODES * NH * 4);
    float* es2  = (float*)alloc((size_t)NNODES * 4);
    float* ed2  = (float*)alloc((size_t)NNODES * 4);
    int*   deg  = (int*)alloc((size_t)NNODES * 4);
    int*   rs   = (int*)alloc((size_t)(NNODES + 1) * 4);
    int*   cur  = (int*)alloc((size_t)NNODES * 4);
    int*   csr  = (int*)alloc((size_t)ETOT * 4);

    // CSR build
    hipMemsetAsync(deg, 0, (size_t)NNODES * 4, stream);
    count_deg<<<(ETOT + 255) / 256, 256, 0, stream>>>(ei, deg);
    scan_deg<<<1, 1024, 0, stream>>>(deg, rs);
    hipMemcpyAsync(cur, rs, (size_t)NNODES * 4, hipMemcpyDeviceToDevice, stream);
    scatter_edges<<<(ETOT + 255) / 256, 256, 0, stream>>>(ei, cur, csr);

    // layer 1
    gemm_f32<128, 128, 16, 8, 8>
        <<<dim3((NNODES + 127) / 128, D1 / 128), 256, 0, stream>>>(x, W1, h1, NNODES, D1, INC);
    {
        int waves = NNODES * NH;
        dots1<<<(waves * 64 + 255) / 256, 256, 0, stream>>>(h1, as1, ad1, es1, ed1);
    }
    attn1<<<NNODES, 256, 0, stream>>>(h1, es1, ed1, rs, csr, b1, out1);

    // layer 2
    gemm_f32<64, 64, 16, 4, 4>
        <<<dim3((NNODES + 63) / 64, OUTC / 64), 256, 0, stream>>>(out1, W2, h2, NNODES, OUTC, D1);
    {
        int waves = NNODES;
        dots2<<<(waves * 64 + 255) / 256, 256, 0, stream>>>(h2, as2, ad2, es2, ed2);
    }
    attn2<<<NNODES, 128, 0, stream>>>(h2, es2, ed2, rs, csr, b2, out);
}

// Round 4
// 673.211 us; speedup vs baseline: 1.8613x; 1.8613x over previous
//
#include <hip/hip_runtime.h>

#define NNODES 50000
#define NEDGES 800000
#define ETOT   (NNODES + NEDGES)   // 850000 edges incl. self-loops
#define NH     8
#define HID    64
#define D1     512                  // NH*HID
#define INC    512
#define OUTC   128
#define NEG    0.2f
#define MPAD   50048                // 391*128, padded row count for GEMM tiles

typedef __attribute__((ext_vector_type(8))) short short8;
typedef __attribute__((ext_vector_type(4))) float f32x4;

__device__ __forceinline__ float bf2f(ushort u) { return __uint_as_float(((uint)u) << 16); }
__device__ __forceinline__ ushort f2bf(float x) {
    uint u = __float_as_uint(x);
    u += 0x7fffu + ((u >> 16) & 1u);   // round-to-nearest-even
    return (ushort)(u >> 16);
}
__device__ __forceinline__ float leaky(float v) { return v >= 0.f ? v : NEG * v; }
__device__ __forceinline__ unsigned fkey(float v) {
    unsigned u = __float_as_uint(v);
    return (u & 0x80000000u) ? ~u : (u | 0x80000000u);
}
__device__ __forceinline__ float funkey(unsigned k) {
    return __uint_as_float((k & 0x80000000u) ? (k & 0x7fffffffu) : ~k);
}

// ---------------- CSR build ----------------
__global__ void count_deg(const int* __restrict__ ei, int* __restrict__ deg) {
    int i = blockIdx.x * 256 + threadIdx.x;
    if (i >= ETOT) return;
    int dst = (i < NEDGES) ? ei[NEDGES + i] : (i - NEDGES);
    atomicAdd(&deg[dst], 1);
}

__global__ void scan_deg(const int* __restrict__ deg, int* __restrict__ rs) {
    __shared__ int part[1024];
    const int n = NNODES;
    const int CH = (n + 1023) / 1024;
    int t = threadIdx.x;
    int lo = t * CH, hi = min(lo + CH, n);
    int s = 0;
    for (int i = lo; i < hi; ++i) s += deg[i];
    part[t] = s;
    __syncthreads();
    for (int off = 1; off < 1024; off <<= 1) {
        int v = (t >= off) ? part[t - off] : 0;
        __syncthreads();
        part[t] += v;
        __syncthreads();
    }
    int run = (t == 0) ? 0 : part[t - 1];
    for (int i = lo; i < hi; ++i) { rs[i] = run; run += deg[i]; }
    if (hi == n) rs[n] = run;
}

__global__ void scatter_edges(const int* __restrict__ ei, int* __restrict__ cursor,
                              int* __restrict__ csr_src) {
    int i = blockIdx.x * 256 + threadIdx.x;
    if (i >= ETOT) return;
    int src, dst;
    if (i < NEDGES) { src = ei[i]; dst = ei[NEDGES + i]; }
    else            { src = dst = i - NEDGES; }
    int pos = atomicAdd(&cursor[dst], 1);
    csr_src[pos] = src;
}

// ---------------- dtype prep ----------------
__global__ void cast_bf16(const float* __restrict__ x, ushort* __restrict__ xb, int n4) {
    int i = blockIdx.x * 256 + threadIdx.x;
    if (i >= n4) return;
    float4 v = *(const float4*)&x[(size_t)i * 4];
    ushort4 o = { f2bf(v.x), f2bf(v.y), f2bf(v.z), f2bf(v.w) };
    *(ushort4*)&xb[(size_t)i * 4] = o;
}

// WT[n][k] = W[k][n], bf16 out.
__global__ void cast_wT(const float* __restrict__ W, ushort* __restrict__ WT, int K, int N) {
    int idx = blockIdx.x * 256 + threadIdx.x;
    if (idx >= K * N) return;
    int n = idx / K, k = idx - n * K;
    WT[idx] = f2bf(W[(size_t)k * N + n]);
}

// ---------------- bf16 MFMA GEMM: C[M,N] = A[M,K] @ Bt[N,K]^T ----------------
// 128x128 tile, BK=64, 4 waves (2x2), 16x16x32 MFMA, global_load_lds staging.
template<int KDIM>
__global__ __launch_bounds__(256) void gemm_bf16(const ushort* __restrict__ A,
                                                 const ushort* __restrict__ Bt,
                                                 ushort* __restrict__ C,
                                                 int M, int N) {
    __shared__ __align__(16) ushort Asl[128 * 64];
    __shared__ __align__(16) ushort Bsl[128 * 64];
    const int tid  = threadIdx.x;
    const int lane = tid & 63;
    const int wid  = tid >> 6;
    const int wr   = wid >> 1, wc = wid & 1;
    const int fr   = lane & 15, fq = lane >> 4;
    const int m0   = blockIdx.x * 128;
    const int n0   = blockIdx.y * 128;

    f32x4 acc[4][4] = {};

    for (int k0 = 0; k0 < KDIM; k0 += 64) {
        __syncthreads();   // previous LDS consumption done
        // stage A tile [128][64] and Bt tile [128][64]: 16 chunks of 1KB each
        #pragma unroll
        for (int i = 0; i < 4; ++i) {
            int chunk = wid * 4 + i;
            int r = chunk * 8 + (lane >> 3);
            const ushort* ga = A  + (size_t)(m0 + r) * KDIM + k0 + (lane & 7) * 8;
            const ushort* gb = Bt + (size_t)(n0 + r) * KDIM + k0 + (lane & 7) * 8;
            __builtin_amdgcn_global_load_lds(
                (const __attribute__((address_space(1))) void*)ga,
                (__attribute__((address_space(3))) void*)(Asl + chunk * 512), 16, 0, 0);
            __builtin_amdgcn_global_load_lds(
                (const __attribute__((address_space(1))) void*)gb,
                (__attribute__((address_space(3))) void*)(Bsl + chunk * 512), 16, 0, 0);
        }
        __syncthreads();   // staged data visible (compiler drains vmcnt)
        #pragma unroll
        for (int ks = 0; ks < 2; ++ks) {
            short8 a[4], b[4];
            #pragma unroll
            for (int m = 0; m < 4; ++m)
                a[m] = *(const short8*)&Asl[(wr * 64 + m * 16 + fr) * 64 + ks * 32 + fq * 8];
            #pragma unroll
            for (int n = 0; n < 4; ++n)
                b[n] = *(const short8*)&Bsl[(wc * 64 + n * 16 + fr) * 64 + ks * 32 + fq * 8];
            #pragma unroll
            for (int m = 0; m < 4; ++m)
                #pragma unroll
                for (int n = 0; n < 4; ++n)
                    acc[m][n] = __builtin_amdgcn_mfma_f32_16x16x32_bf16(a[m], b[n], acc[m][n], 0, 0, 0);
        }
    }
    // epilogue: C row = m0 + wr*64 + m*16 + fq*4 + r ; col = n0 + wc*64 + n*16 + fr
    #pragma unroll
    for (int m = 0; m < 4; ++m) {
        #pragma unroll
        for (int r = 0; r < 4; ++r) {
            int row = m0 + wr * 64 + m * 16 + fq * 4 + r;
            if (row >= M) continue;
            #pragma unroll
            for (int n = 0; n < 4; ++n)
                C[(size_t)row * N + n0 + wc * 64 + n * 16 + fr] = f2bf(acc[m][n][r]);
        }
    }
}

// ---------------- attention dot products ----------------
// layer 1: one wave per node, lane covers 8 channels; head = lane>>3
__global__ void dots1(const ushort* __restrict__ h1, const float* __restrict__ a_src,
                      const float* __restrict__ a_dst,
                      float* __restrict__ es, float* __restrict__ ed) {
    int gw   = (blockIdx.x * blockDim.x + threadIdx.x) >> 6;
    int lane = threadIdx.x & 63;
    if (gw >= NNODES) return;
    short8 v = *(const short8*)&h1[(size_t)gw * D1 + lane * 8];
    int h = lane >> 3, c0 = (lane & 7) * 8;
    float s = 0.f, d = 0.f;
    #pragma unroll
    for (int j = 0; j < 8; ++j) {
        float x = bf2f((ushort)v[j]);
        s += x * a_src[h * HID + c0 + j];
        d += x * a_dst[h * HID + c0 + j];
    }
    #pragma unroll
    for (int off = 1; off < 8; off <<= 1) {
        s += __shfl_xor(s, off);
        d += __shfl_xor(d, off);
    }
    if ((lane & 7) == 0) { es[gw * NH + h] = s; ed[gw * NH + h] = d; }
}

// layer 2: one wave per node, 128 channels; lane covers 2 channels
__global__ void dots2(const ushort* __restrict__ h2, const float* __restrict__ a_src,
                      const float* __restrict__ a_dst,
                      float* __restrict__ es, float* __restrict__ ed) {
    int gw   = (blockIdx.x * blockDim.x + threadIdx.x) >> 6;
    int lane = threadIdx.x & 63;
    if (gw >= NNODES) return;
    uint u = *(const uint*)&h2[(size_t)gw * OUTC + lane * 2];
    float x0 = bf2f((ushort)(u & 0xffffu)), x1 = bf2f((ushort)(u >> 16));
    float s = x0 * a_src[lane * 2] + x1 * a_src[lane * 2 + 1];
    float d = x0 * a_dst[lane * 2] + x1 * a_dst[lane * 2 + 1];
    #pragma unroll
    for (int off = 1; off < 64; off <<= 1) {
        s += __shfl_xor(s, off);
        d += __shfl_xor(d, off);
    }
    if (lane == 0) { es[gw] = s; ed[gw] = d; }
}

// ---------------- layer-1 aggregation: one block (256 thr) per dst node ----------------
#define CAP1 128
__global__ __launch_bounds__(256) void attn1(const ushort* __restrict__ h1,
                                             const float* __restrict__ esrc,
                                             const float* __restrict__ edst,
                                             const int* __restrict__ rs,
                                             const int* __restrict__ csr_src,
                                             const float* __restrict__ b1,
                                             ushort* __restrict__ out1) {
    int n = blockIdx.x;
    int t = threadIdx.x;
    int beg = rs[n], deg = rs[n + 1] - beg;
    __shared__ float alpha_sh[CAP1][NH];   // 4KB
    __shared__ unsigned mkey[NH];
    __shared__ float msh[NH], ssh[NH], rinv[NH];
    if (t < NH) { mkey[t] = 0u; ssh[t] = 0.f; }
    __syncthreads();
    // pass A: per-head max (and cache v)
    for (int idx = t; idx < deg * NH; idx += 256) {
        int e = idx >> 3, h = idx & 7;
        int s = csr_src[beg + e];
        float v = leaky(esrc[s * NH + h] + edst[n * NH + h]);
        atomicMax(&mkey[h], fkey(v));
        if (e < CAP1) alpha_sh[e][h] = v;
    }
    __syncthreads();
    if (t < NH) msh[t] = funkey(mkey[t]);
    __syncthreads();
    // pass B: per-head sum of exp; cache p
    for (int idx = t; idx < deg * NH; idx += 256) {
        int e = idx >> 3, h = idx & 7;
        float v;
        if (e < CAP1) v = alpha_sh[e][h];
        else {
            int s = csr_src[beg + e];
            v = leaky(esrc[s * NH + h] + edst[n * NH + h]);
        }
        float p = __expf(v - msh[h]);
        atomicAdd(&ssh[h], p);
        if (e < CAP1) alpha_sh[e][h] = p;
    }
    __syncthreads();
    if (t < NH) rinv[t] = 1.f / (ssh[t] + 1e-16f);
    __syncthreads();
    // pass C: thread owns channels 2t, 2t+1 (same head h = t>>5)
    int c0 = 2 * t;
    int h = t >> 5;
    float m = msh[h], ri = rinv[h], edn = edst[n * NH + h];
    float acc0 = 0.f, acc1 = 0.f;
    for (int e = 0; e < deg; ++e) {
        int s = csr_src[beg + e];
        float a;
        if (e < CAP1) a = alpha_sh[e][h];
        else          a = __expf(leaky(esrc[s * NH + h] + edn) - m);
        uint u = *(const uint*)&h1[(size_t)s * D1 + c0];
        acc0 += a * bf2f((ushort)(u & 0xffffu));
        acc1 += a * bf2f((ushort)(u >> 16));
    }
    float o0 = fmaxf(acc0 * ri + b1[c0], 0.f);
    float o1 = fmaxf(acc1 * ri + b1[c0 + 1], 0.f);
    uint pk = (uint)f2bf(o0) | ((uint)f2bf(o1) << 16);
    *(uint*)&out1[(size_t)n * D1 + c0] = pk;
}

// ---------------- layer-2 aggregation: one block (128 thr) per dst node ----------------
#define CAP2 128
__global__ __launch_bounds__(128) void attn2(const ushort* __restrict__ h2,
                                             const float* __restrict__ esrc,
                                             const float* __restrict__ edst,
                                             const int* __restrict__ rs,
                                             const int* __restrict__ csr_src,
                                             const float* __restrict__ b2,
                                             float* __restrict__ out) {
    int n = blockIdx.x;
    int t = threadIdx.x;
    int beg = rs[n], deg = rs[n + 1] - beg;
    __shared__ float alpha_sh[CAP2];
    __shared__ unsigned mkey;
    __shared__ float msh, ssh, rinv;
    if (t == 0) { mkey = 0u; ssh = 0.f; }
    __syncthreads();
    float edn = edst[n];
    for (int e = t; e < deg; e += 128) {
        int s = csr_src[beg + e];
        float v = leaky(esrc[s] + edn);
        atomicMax(&mkey, fkey(v));
        if (e < CAP2) alpha_sh[e] = v;
    }
    __syncthreads();
    if (t == 0) msh = funkey(mkey);
    __syncthreads();
    for (int e = t; e < deg; e += 128) {
        float v;
        if (e < CAP2) v = alpha_sh[e];
        else { int s = csr_src[beg + e]; v = leaky(esrc[s] + edn); }
        float p = __expf(v - msh);
        atomicAdd(&ssh, p);
        if (e < CAP2) alpha_sh[e] = p;
    }
    __syncthreads();
    if (t == 0) rinv = 1.f / (ssh + 1e-16f);
    __syncthreads();
    float m = msh, ri = rinv;
    float acc = 0.f;
    for (int e = 0; e < deg; ++e) {
        int s = csr_src[beg + e];
        float a = (e < CAP2) ? alpha_sh[e] : __expf(leaky(esrc[s] + edn) - m);
        acc += a * bf2f(h2[(size_t)s * OUTC + t]);
    }
    out[(size_t)n * OUTC + t] = acc * ri + b2[t];
}

// ---------------- launch ----------------
extern "C" void kernel_launch(void* const* d_in, const int* in_sizes, int n_in,
                              void* d_out, int out_size, void* d_ws, size_t ws_size,
                              hipStream_t stream) {
    const float* x   = (const float*)d_in[0];
    const int*   ei  = (const int*)  d_in[1];
    const float* W1  = (const float*)d_in[2];
    const float* b1  = (const float*)d_in[3];
    const float* as1 = (const float*)d_in[4];
    const float* ad1 = (const float*)d_in[5];
    const float* W2  = (const float*)d_in[6];
    const float* b2  = (const float*)d_in[7];
    const float* as2 = (const float*)d_in[8];
    const float* ad2 = (const float*)d_in[9];
    float* out = (float*)d_out;

    char* ws = (char*)d_ws;
    size_t off = 0;
    auto alloc = [&](size_t bytes) -> void* {
        void* p = ws + off;
        off = (off + bytes + 255) & ~(size_t)255;
        return p;
    };
    ushort* xb    = (ushort*)alloc((size_t)MPAD * INC * 2);
    ushort* w1t   = (ushort*)alloc((size_t)D1 * INC * 2);
    ushort* w2t   = (ushort*)alloc((size_t)OUTC * D1 * 2);
    ushort* h1b   = (ushort*)alloc((size_t)MPAD * D1 * 2);
    ushort* out1b = (ushort*)alloc((size_t)MPAD * D1 * 2);
    ushort* h2b   = (ushort*)alloc((size_t)MPAD * OUTC * 2);
    float*  es1   = (float*)alloc((size_t)NNODES * NH * 4);
    float*  ed1   = (float*)alloc((size_t)NNODES * NH * 4);
    float*  es2   = (float*)alloc((size_t)NNODES * 4);
    float*  ed2   = (float*)alloc((size_t)NNODES * 4);
    int*    deg   = (int*)alloc((size_t)NNODES * 4);
    int*    rs    = (int*)alloc((size_t)(NNODES + 1) * 4);
    int*    cur   = (int*)alloc((size_t)NNODES * 4);
    int*    csr   = (int*)alloc((size_t)ETOT * 4);

    // CSR build
    hipMemsetAsync(deg, 0, (size_t)NNODES * 4, stream);
    count_deg<<<(ETOT + 255) / 256, 256, 0, stream>>>(ei, deg);
    scan_deg<<<1, 1024, 0, stream>>>(deg, rs);
    hipMemcpyAsync(cur, rs, (size_t)NNODES * 4, hipMemcpyDeviceToDevice, stream);
    scatter_edges<<<(ETOT + 255) / 256, 256, 0, stream>>>(ei, cur, csr);

    // dtype prep
    cast_bf16<<<(NNODES * INC / 4 + 255) / 256, 256, 0, stream>>>(x, xb, NNODES * INC / 4);
    cast_wT<<<(INC * D1 + 255) / 256, 256, 0, stream>>>(W1, w1t, INC, D1);
    cast_wT<<<(D1 * OUTC + 255) / 256, 256, 0, stream>>>(W2, w2t, D1, OUTC);

    // layer 1
    gemm_bf16<INC><<<dim3(MPAD / 128, D1 / 128), 256, 0, stream>>>(xb, w1t, h1b, NNODES, D1);
    dots1<<<(NNODES * 64 + 255) / 256, 256, 0, stream>>>(h1b, as1, ad1, es1, ed1);
    attn1<<<NNODES, 256, 0, stream>>>(h1b, es1, ed1, rs, csr, b1, out1b);

    // layer 2
    gemm_bf16<D1><<<dim3(MPAD / 128, OUTC / 128), 256, 0, stream>>>(out1b, w2t, h2b, NNODES, OUTC);
    dots2<<<(NNODES * 64 + 255) / 256, 256, 0, stream>>>(h2b, as2, ad2, es2, ed2);
    attn2<<<NNODES, 128, 0, stream>>>(h2b, es2, ed2, rs, csr, b2, out);
}

// Round 5
// 611.370 us; speedup vs baseline: 2.0496x; 1.1012x over previous
//
#include <hip/hip_runtime.h>

#define NNODES 50000
#define NEDGES 800000
#define ETOT   (NNODES + NEDGES)   // 850000 edges incl. self-loops
#define NH     8
#define HID    64
#define D1     512                  // NH*HID
#define INC    512
#define OUTC   128
#define NEG    0.2f
#define MPAD   50048                // 391*128, padded row count for GEMM tiles

typedef __attribute__((ext_vector_type(8))) short short8;
typedef __attribute__((ext_vector_type(4))) float f32x4;

__device__ __forceinline__ float bf2f(ushort u) { return __uint_as_float(((uint)u) << 16); }
__device__ __forceinline__ ushort f2bf(float x) {
    uint u = __float_as_uint(x);
    u += 0x7fffu + ((u >> 16) & 1u);   // round-to-nearest-even
    return (ushort)(u >> 16);
}
__device__ __forceinline__ float leaky(float v) { return v >= 0.f ? v : NEG * v; }

// ---------------- CSR build ----------------
__global__ void count_deg(const int* __restrict__ ei, int* __restrict__ deg) {
    int i = blockIdx.x * 256 + threadIdx.x;
    if (i >= ETOT) return;
    int dst = (i < NEDGES) ? ei[NEDGES + i] : (i - NEDGES);
    atomicAdd(&deg[dst], 1);
}

__global__ void scan_deg(const int* __restrict__ deg, int* __restrict__ rs) {
    __shared__ int part[1024];
    const int n = NNODES;
    const int CH = (n + 1023) / 1024;
    int t = threadIdx.x;
    int lo = t * CH, hi = min(lo + CH, n);
    int s = 0;
    for (int i = lo; i < hi; ++i) s += deg[i];
    part[t] = s;
    __syncthreads();
    for (int off = 1; off < 1024; off <<= 1) {
        int v = (t >= off) ? part[t - off] : 0;
        __syncthreads();
        part[t] += v;
        __syncthreads();
    }
    int run = (t == 0) ? 0 : part[t - 1];
    for (int i = lo; i < hi; ++i) { rs[i] = run; run += deg[i]; }
    if (hi == n) rs[n] = run;
}

__global__ void scatter_edges(const int* __restrict__ ei, int* __restrict__ cursor,
                              int* __restrict__ csr_src) {
    int i = blockIdx.x * 256 + threadIdx.x;
    if (i >= ETOT) return;
    int src, dst;
    if (i < NEDGES) { src = ei[i]; dst = ei[NEDGES + i]; }
    else            { src = dst = i - NEDGES; }
    int pos = atomicAdd(&cursor[dst], 1);
    csr_src[pos] = src;
}

// ---------------- dtype prep ----------------
__global__ void cast_bf16(const float* __restrict__ x, ushort* __restrict__ xb, int n4) {
    int i = blockIdx.x * 256 + threadIdx.x;
    if (i >= n4) return;
    float4 v = *(const float4*)&x[(size_t)i * 4];
    ushort4 o = { f2bf(v.x), f2bf(v.y), f2bf(v.z), f2bf(v.w) };
    *(ushort4*)&xb[(size_t)i * 4] = o;
}

// WT[n][k] = W[k][n], bf16 out.
__global__ void cast_wT(const float* __restrict__ W, ushort* __restrict__ WT, int K, int N) {
    int idx = blockIdx.x * 256 + threadIdx.x;
    if (idx >= K * N) return;
    int n = idx / K, k = idx - n * K;
    WT[idx] = f2bf(W[(size_t)k * N + n]);
}

// ---------------- bf16 MFMA GEMM: C[M,N] = A[M,K] @ Bt[N,K]^T ----------------
// 128x128 tile, BK=64, 4 waves (2x2), 16x16x32 MFMA, global_load_lds staging.
template<int KDIM>
__global__ __launch_bounds__(256) void gemm_bf16(const ushort* __restrict__ A,
                                                 const ushort* __restrict__ Bt,
                                                 ushort* __restrict__ C,
                                                 int M, int N) {
    __shared__ __align__(16) ushort Asl[128 * 64];
    __shared__ __align__(16) ushort Bsl[128 * 64];
    const int tid  = threadIdx.x;
    const int lane = tid & 63;
    const int wid  = tid >> 6;
    const int wr   = wid >> 1, wc = wid & 1;
    const int fr   = lane & 15, fq = lane >> 4;
    const int m0   = blockIdx.x * 128;
    const int n0   = blockIdx.y * 128;

    f32x4 acc[4][4] = {};

    for (int k0 = 0; k0 < KDIM; k0 += 64) {
        __syncthreads();   // previous LDS consumption done
        #pragma unroll
        for (int i = 0; i < 4; ++i) {
            int chunk = wid * 4 + i;
            int r = chunk * 8 + (lane >> 3);
            const ushort* ga = A  + (size_t)(m0 + r) * KDIM + k0 + (lane & 7) * 8;
            const ushort* gb = Bt + (size_t)(n0 + r) * KDIM + k0 + (lane & 7) * 8;
            __builtin_amdgcn_global_load_lds(
                (const __attribute__((address_space(1))) void*)ga,
                (__attribute__((address_space(3))) void*)(Asl + chunk * 512), 16, 0, 0);
            __builtin_amdgcn_global_load_lds(
                (const __attribute__((address_space(1))) void*)gb,
                (__attribute__((address_space(3))) void*)(Bsl + chunk * 512), 16, 0, 0);
        }
        __syncthreads();   // staged data visible (compiler drains vmcnt)
        #pragma unroll
        for (int ks = 0; ks < 2; ++ks) {
            short8 a[4], b[4];
            #pragma unroll
            for (int m = 0; m < 4; ++m)
                a[m] = *(const short8*)&Asl[(wr * 64 + m * 16 + fr) * 64 + ks * 32 + fq * 8];
            #pragma unroll
            for (int n = 0; n < 4; ++n)
                b[n] = *(const short8*)&Bsl[(wc * 64 + n * 16 + fr) * 64 + ks * 32 + fq * 8];
            #pragma unroll
            for (int m = 0; m < 4; ++m)
                #pragma unroll
                for (int n = 0; n < 4; ++n)
                    acc[m][n] = __builtin_amdgcn_mfma_f32_16x16x32_bf16(a[m], b[n], acc[m][n], 0, 0, 0);
        }
    }
    #pragma unroll
    for (int m = 0; m < 4; ++m) {
        #pragma unroll
        for (int r = 0; r < 4; ++r) {
            int row = m0 + wr * 64 + m * 16 + fq * 4 + r;
            if (row >= M) continue;
            #pragma unroll
            for (int n = 0; n < 4; ++n)
                C[(size_t)row * N + n0 + wc * 64 + n * 16 + fr] = f2bf(acc[m][n][r]);
        }
    }
}

// ---------------- attention dot products ----------------
__global__ void dots1(const ushort* __restrict__ h1, const float* __restrict__ a_src,
                      const float* __restrict__ a_dst,
                      float* __restrict__ es, float* __restrict__ ed) {
    int gw   = (blockIdx.x * blockDim.x + threadIdx.x) >> 6;
    int lane = threadIdx.x & 63;
    if (gw >= NNODES) return;
    short8 v = *(const short8*)&h1[(size_t)gw * D1 + lane * 8];
    int h = lane >> 3, c0 = (lane & 7) * 8;
    float s = 0.f, d = 0.f;
    #pragma unroll
    for (int j = 0; j < 8; ++j) {
        float x = bf2f((ushort)v[j]);
        s += x * a_src[h * HID + c0 + j];
        d += x * a_dst[h * HID + c0 + j];
    }
    #pragma unroll
    for (int off = 1; off < 8; off <<= 1) {
        s += __shfl_xor(s, off);
        d += __shfl_xor(d, off);
    }
    if ((lane & 7) == 0) { es[gw * NH + h] = s; ed[gw * NH + h] = d; }
}

__global__ void dots2(const ushort* __restrict__ h2, const float* __restrict__ a_src,
                      const float* __restrict__ a_dst,
                      float* __restrict__ es, float* __restrict__ ed) {
    int gw   = (blockIdx.x * blockDim.x + threadIdx.x) >> 6;
    int lane = threadIdx.x & 63;
    if (gw >= NNODES) return;
    uint u = *(const uint*)&h2[(size_t)gw * OUTC + lane * 2];
    float x0 = bf2f((ushort)(u & 0xffffu)), x1 = bf2f((ushort)(u >> 16));
    float s = x0 * a_src[lane * 2] + x1 * a_src[lane * 2 + 1];
    float d = x0 * a_dst[lane * 2] + x1 * a_dst[lane * 2 + 1];
    #pragma unroll
    for (int off = 1; off < 64; off <<= 1) {
        s += __shfl_xor(s, off);
        d += __shfl_xor(d, off);
    }
    if (lane == 0) { es[gw] = s; ed[gw] = d; }
}

// ---------------- layer-1 aggregation ----------------
// one block (256 thr = 4 waves) per dst node. Wave-parallel softmax (wave owns
// 2 heads, float2 esrc loads, shfl reduction), LDS-staged alpha+src, then
// unroll-4 gather (4 outstanding loads/thread).
#define CAP1 128
__global__ __launch_bounds__(256) void attn1(const ushort* __restrict__ h1,
                                             const float* __restrict__ esrc,
                                             const float* __restrict__ edst,
                                             const int* __restrict__ rs,
                                             const int* __restrict__ csr_src,
                                             const float* __restrict__ b1,
                                             ushort* __restrict__ out1) {
    int n = blockIdx.x;
    int t = threadIdx.x;
    int lane = t & 63, wid = t >> 6;
    int beg = rs[n], deg = rs[n + 1] - beg;
    int dcap = min(deg, CAP1);
    __shared__ float alpha_sh[NH][CAP1];   // [head][edge] — stride-1 in e, conflict-free
    __shared__ int   ssrc_sh[CAP1];
    __shared__ float msh[NH], rinv_sh[NH];

    // stage src indices
    for (int e = t; e < dcap; e += 256) ssrc_sh[e] = csr_src[beg + e];
    __syncthreads();

    // wave wid handles heads 2*wid, 2*wid+1
    {
        int h0 = wid * 2;
        float edn0 = edst[n * NH + h0], edn1 = edst[n * NH + h0 + 1];
        float m0 = -1e30f, m1 = -1e30f;
        for (int e = lane; e < deg; e += 64) {
            int s = (e < CAP1) ? ssrc_sh[e] : csr_src[beg + e];
            float2 es2 = *(const float2*)&esrc[s * NH + h0];
            float v0 = leaky(es2.x + edn0), v1 = leaky(es2.y + edn1);
            if (e < CAP1) { alpha_sh[h0][e] = v0; alpha_sh[h0 + 1][e] = v1; }
            m0 = fmaxf(m0, v0); m1 = fmaxf(m1, v1);
        }
        #pragma unroll
        for (int off = 32; off; off >>= 1) {
            m0 = fmaxf(m0, __shfl_xor(m0, off));
            m1 = fmaxf(m1, __shfl_xor(m1, off));
        }
        float s0 = 0.f, s1 = 0.f;
        for (int e = lane; e < deg; e += 64) {
            float v0, v1;
            if (e < CAP1) { v0 = alpha_sh[h0][e]; v1 = alpha_sh[h0 + 1][e]; }
            else {
                int s = csr_src[beg + e];
                float2 es2 = *(const float2*)&esrc[s * NH + h0];
                v0 = leaky(es2.x + edn0); v1 = leaky(es2.y + edn1);
            }
            float p0 = __expf(v0 - m0), p1 = __expf(v1 - m1);
            if (e < CAP1) { alpha_sh[h0][e] = p0; alpha_sh[h0 + 1][e] = p1; }
            s0 += p0; s1 += p1;
        }
        #pragma unroll
        for (int off = 32; off; off >>= 1) {
            s0 += __shfl_xor(s0, off);
            s1 += __shfl_xor(s1, off);
        }
        if (lane == 0) {
            msh[h0] = m0; msh[h0 + 1] = m1;
            rinv_sh[h0] = 1.f / (s0 + 1e-16f);
            rinv_sh[h0 + 1] = 1.f / (s1 + 1e-16f);
        }
    }
    __syncthreads();

    // gather: thread owns channels 2t, 2t+1 (head h = t>>5)
    int c0 = 2 * t;
    int h = t >> 5;
    float m = msh[h], ri = rinv_sh[h];
    float edn = edst[n * NH + h];
    float acc0 = 0.f, acc1 = 0.f;
    int e = 0;
    for (; e + 4 <= dcap; e += 4) {
        int s0i = ssrc_sh[e], s1i = ssrc_sh[e + 1], s2i = ssrc_sh[e + 2], s3i = ssrc_sh[e + 3];
        uint u0 = *(const uint*)&h1[(size_t)s0i * D1 + c0];
        uint u1 = *(const uint*)&h1[(size_t)s1i * D1 + c0];
        uint u2 = *(const uint*)&h1[(size_t)s2i * D1 + c0];
        uint u3 = *(const uint*)&h1[(size_t)s3i * D1 + c0];
        float a0 = alpha_sh[h][e], a1 = alpha_sh[h][e + 1];
        float a2 = alpha_sh[h][e + 2], a3 = alpha_sh[h][e + 3];
        acc0 += a0 * bf2f((ushort)(u0 & 0xffffu)) + a1 * bf2f((ushort)(u1 & 0xffffu))
              + a2 * bf2f((ushort)(u2 & 0xffffu)) + a3 * bf2f((ushort)(u3 & 0xffffu));
        acc1 += a0 * bf2f((ushort)(u0 >> 16)) + a1 * bf2f((ushort)(u1 >> 16))
              + a2 * bf2f((ushort)(u2 >> 16)) + a3 * bf2f((ushort)(u3 >> 16));
    }
    for (; e < dcap; ++e) {
        int s = ssrc_sh[e];
        float a = alpha_sh[h][e];
        uint u = *(const uint*)&h1[(size_t)s * D1 + c0];
        acc0 += a * bf2f((ushort)(u & 0xffffu));
        acc1 += a * bf2f((ushort)(u >> 16));
    }
    for (; e < deg; ++e) {   // overflow path (deg > CAP1, essentially never)
        int s = csr_src[beg + e];
        float a = __expf(leaky(esrc[s * NH + h] + edn) - m);
        uint u = *(const uint*)&h1[(size_t)s * D1 + c0];
        acc0 += a * bf2f((ushort)(u & 0xffffu));
        acc1 += a * bf2f((ushort)(u >> 16));
    }
    float o0 = fmaxf(acc0 * ri + b1[c0], 0.f);
    float o1 = fmaxf(acc1 * ri + b1[c0 + 1], 0.f);
    uint pk = (uint)f2bf(o0) | ((uint)f2bf(o1) << 16);
    *(uint*)&out1[(size_t)n * D1 + c0] = pk;
}

// ---------------- layer-2 aggregation ----------------
// one wave per node (4 nodes per 256-block); no barriers; lane owns 2 channels.
#define CAP2 128
__global__ __launch_bounds__(256) void attn2(const ushort* __restrict__ h2,
                                             const float* __restrict__ esrc,
                                             const float* __restrict__ edst,
                                             const int* __restrict__ rs,
                                             const int* __restrict__ csr_src,
                                             const float* __restrict__ b2,
                                             float* __restrict__ out) {
    int lane = threadIdx.x & 63, wid = threadIdx.x >> 6;
    int n = blockIdx.x * 4 + wid;
    if (n >= NNODES) return;
    int beg = rs[n], deg = rs[n + 1] - beg;
    int dcap = min(deg, CAP2);
    __shared__ float al_sh[4][CAP2];
    __shared__ int   ss_sh[4][CAP2];
    float* al = al_sh[wid];
    int*   ss = ss_sh[wid];

    for (int e = lane; e < dcap; e += 64) ss[e] = csr_src[beg + e];
    // (wave-private LDS slice: no barrier needed; compiler inserts lgkmcnt waits)

    float edn = edst[n];
    float m = -1e30f;
    for (int e = lane; e < deg; e += 64) {
        int s = (e < CAP2) ? ss[e] : csr_src[beg + e];
        float v = leaky(esrc[s] + edn);
        if (e < CAP2) al[e] = v;
        m = fmaxf(m, v);
    }
    #pragma unroll
    for (int off = 32; off; off >>= 1) m = fmaxf(m, __shfl_xor(m, off));
    float ssum = 0.f;
    for (int e = lane; e < deg; e += 64) {
        float v = (e < CAP2) ? al[e] : leaky(esrc[csr_src[beg + e]] + edn);
        float p = __expf(v - m);
        if (e < CAP2) al[e] = p;
        ssum += p;
    }
    #pragma unroll
    for (int off = 32; off; off >>= 1) ssum += __shfl_xor(ssum, off);
    float ri = 1.f / (ssum + 1e-16f);

    int c0 = 2 * lane;
    float acc0 = 0.f, acc1 = 0.f;
    int e = 0;
    for (; e + 4 <= dcap; e += 4) {
        int s0i = ss[e], s1i = ss[e + 1], s2i = ss[e + 2], s3i = ss[e + 3];
        uint u0 = *(const uint*)&h2[(size_t)s0i * OUTC + c0];
        uint u1 = *(const uint*)&h2[(size_t)s1i * OUTC + c0];
        uint u2 = *(const uint*)&h2[(size_t)s2i * OUTC + c0];
        uint u3 = *(const uint*)&h2[(size_t)s3i * OUTC + c0];
        float a0 = al[e], a1 = al[e + 1], a2 = al[e + 2], a3 = al[e + 3];
        acc0 += a0 * bf2f((ushort)(u0 & 0xffffu)) + a1 * bf2f((ushort)(u1 & 0xffffu))
              + a2 * bf2f((ushort)(u2 & 0xffffu)) + a3 * bf2f((ushort)(u3 & 0xffffu));
        acc1 += a0 * bf2f((ushort)(u0 >> 16)) + a1 * bf2f((ushort)(u1 >> 16))
              + a2 * bf2f((ushort)(u2 >> 16)) + a3 * bf2f((ushort)(u3 >> 16));
    }
    for (; e < dcap; ++e) {
        int s = ss[e];
        float a = al[e];
        uint u = *(const uint*)&h2[(size_t)s * OUTC + c0];
        acc0 += a * bf2f((ushort)(u & 0xffffu));
        acc1 += a * bf2f((ushort)(u >> 16));
    }
    for (; e < deg; ++e) {   // overflow path
        int s = csr_src[beg + e];
        float a = __expf(leaky(esrc[s] + edn) - m);
        uint u = *(const uint*)&h2[(size_t)s * OUTC + c0];
        acc0 += a * bf2f((ushort)(u & 0xffffu));
        acc1 += a * bf2f((ushort)(u >> 16));
    }
    float2 o = { acc0 * ri + b2[c0], acc1 * ri + b2[c0 + 1] };
    *(float2*)&out[(size_t)n * OUTC + c0] = o;
}

// ---------------- launch ----------------
extern "C" void kernel_launch(void* const* d_in, const int* in_sizes, int n_in,
                              void* d_out, int out_size, void* d_ws, size_t ws_size,
                              hipStream_t stream) {
    const float* x   = (const float*)d_in[0];
    const int*   ei  = (const int*)  d_in[1];
    const float* W1  = (const float*)d_in[2];
    const float* b1  = (const float*)d_in[3];
    const float* as1 = (const float*)d_in[4];
    const float* ad1 = (const float*)d_in[5];
    const float* W2  = (const float*)d_in[6];
    const float* b2  = (const float*)d_in[7];
    const float* as2 = (const float*)d_in[8];
    const float* ad2 = (const float*)d_in[9];
    float* out = (float*)d_out;

    char* ws = (char*)d_ws;
    size_t off = 0;
    auto alloc = [&](size_t bytes) -> void* {
        void* p = ws + off;
        off = (off + bytes + 255) & ~(size_t)255;
        return p;
    };
    ushort* xb    = (ushort*)alloc((size_t)MPAD * INC * 2);
    ushort* w1t   = (ushort*)alloc((size_t)D1 * INC * 2);
    ushort* w2t   = (ushort*)alloc((size_t)OUTC * D1 * 2);
    ushort* h1b   = (ushort*)alloc((size_t)MPAD * D1 * 2);
    ushort* out1b = (ushort*)alloc((size_t)MPAD * D1 * 2);
    ushort* h2b   = (ushort*)alloc((size_t)MPAD * OUTC * 2);
    float*  es1   = (float*)alloc((size_t)NNODES * NH * 4);
    float*  ed1   = (float*)alloc((size_t)NNODES * NH * 4);
    float*  es2   = (float*)alloc((size_t)NNODES * 4);
    float*  ed2   = (float*)alloc((size_t)NNODES * 4);
    int*    deg   = (int*)alloc((size_t)NNODES * 4);
    int*    rs    = (int*)alloc((size_t)(NNODES + 1) * 4);
    int*    cur   = (int*)alloc((size_t)NNODES * 4);
    int*    csr   = (int*)alloc((size_t)ETOT * 4);

    // CSR build
    hipMemsetAsync(deg, 0, (size_t)NNODES * 4, stream);
    count_deg<<<(ETOT + 255) / 256, 256, 0, stream>>>(ei, deg);
    scan_deg<<<1, 1024, 0, stream>>>(deg, rs);
    hipMemcpyAsync(cur, rs, (size_t)NNODES * 4, hipMemcpyDeviceToDevice, stream);
    scatter_edges<<<(ETOT + 255) / 256, 256, 0, stream>>>(ei, cur, csr);

    // dtype prep
    cast_bf16<<<(NNODES * INC / 4 + 255) / 256, 256, 0, stream>>>(x, xb, NNODES * INC / 4);
    cast_wT<<<(INC * D1 + 255) / 256, 256, 0, stream>>>(W1, w1t, INC, D1);
    cast_wT<<<(D1 * OUTC + 255) / 256, 256, 0, stream>>>(W2, w2t, D1, OUTC);

    // layer 1
    gemm_bf16<INC><<<dim3(MPAD / 128, D1 / 128), 256, 0, stream>>>(xb, w1t, h1b, NNODES, D1);
    dots1<<<(NNODES * 64 + 255) / 256, 256, 0, stream>>>(h1b, as1, ad1, es1, ed1);
    attn1<<<NNODES, 256, 0, stream>>>(h1b, es1, ed1, rs, csr, b1, out1b);

    // layer 2
    gemm_bf16<D1><<<dim3(MPAD / 128, OUTC / 128), 256, 0, stream>>>(out1b, w2t, h2b, NNODES, OUTC);
    dots2<<<(NNODES * 64 + 255) / 256, 256, 0, stream>>>(h2b, as2, ad2, es2, ed2);
    attn2<<<(NNODES + 3) / 4, 256, 0, stream>>>(h2b, es2, ed2, rs, csr, b2, out);
}

// Round 6
// 591.213 us; speedup vs baseline: 2.1195x; 1.0341x over previous
//
#include <hip/hip_runtime.h>
#include <hip/hip_fp16.h>

#define NNODES 50000
#define NEDGES 800000
#define ETOT   (NNODES + NEDGES)   // 850000 edges incl. self-loops
#define NH     8
#define HID    64
#define D1     512                  // NH*HID
#define INC    512
#define OUTC   128
#define NEG    0.2f
#define MPAD   50048                // 391*128, padded row count for GEMM tiles

typedef __attribute__((ext_vector_type(8))) short short8;
typedef __attribute__((ext_vector_type(4))) float f32x4;
typedef _Float16 half8v __attribute__((ext_vector_type(8)));
typedef _Float16 half2v __attribute__((ext_vector_type(2)));

__device__ __forceinline__ ushort f2h_bits(float x) {
    _Float16 h = (_Float16)x; return __builtin_bit_cast(ushort, h);
}
__device__ __forceinline__ float h2f(ushort b) {
    return (float)__builtin_bit_cast(_Float16, b);
}
__device__ __forceinline__ uint splat_h2(float p) {
    uint b = (uint)f2h_bits(p); return b | (b << 16);
}
__device__ __forceinline__ half2v as_h2(uint u) { return __builtin_bit_cast(half2v, u); }
__device__ __forceinline__ float leaky(float v) { return v >= 0.f ? v : NEG * v; }

// ---------------- CSR build ----------------
__global__ void count_deg(const int* __restrict__ ei, int* __restrict__ deg) {
    int i = blockIdx.x * 256 + threadIdx.x;
    if (i >= ETOT) return;
    int dst = (i < NEDGES) ? ei[NEDGES + i] : (i - NEDGES);
    atomicAdd(&deg[dst], 1);
}

__global__ void scan_deg(const int* __restrict__ deg, int* __restrict__ rs) {
    __shared__ int part[1024];
    const int n = NNODES;
    const int CH = (n + 1023) / 1024;
    int t = threadIdx.x;
    int lo = t * CH, hi = min(lo + CH, n);
    int s = 0;
    for (int i = lo; i < hi; ++i) s += deg[i];
    part[t] = s;
    __syncthreads();
    for (int off = 1; off < 1024; off <<= 1) {
        int v = (t >= off) ? part[t - off] : 0;
        __syncthreads();
        part[t] += v;
        __syncthreads();
    }
    int run = (t == 0) ? 0 : part[t - 1];
    for (int i = lo; i < hi; ++i) { rs[i] = run; run += deg[i]; }
    if (hi == n) rs[n] = run;
}

__global__ void scatter_edges(const int* __restrict__ ei, int* __restrict__ cursor,
                              int* __restrict__ csr_src) {
    int i = blockIdx.x * 256 + threadIdx.x;
    if (i >= ETOT) return;
    int src, dst;
    if (i < NEDGES) { src = ei[i]; dst = ei[NEDGES + i]; }
    else            { src = dst = i - NEDGES; }
    int pos = atomicAdd(&cursor[dst], 1);
    csr_src[pos] = src;
}

// ---------------- dtype prep (f16) ----------------
__global__ void cast_f16(const float* __restrict__ x, ushort* __restrict__ xh, int n4) {
    int i = blockIdx.x * 256 + threadIdx.x;
    if (i >= n4) return;
    float4 v = *(const float4*)&x[(size_t)i * 4];
    ushort4 o = { f2h_bits(v.x), f2h_bits(v.y), f2h_bits(v.z), f2h_bits(v.w) };
    *(ushort4*)&xh[(size_t)i * 4] = o;
}

// WT[n][k] = W[k][n], f16 out.
__global__ void cast_wT(const float* __restrict__ W, ushort* __restrict__ WT, int K, int N) {
    int idx = blockIdx.x * 256 + threadIdx.x;
    if (idx >= K * N) return;
    int n = idx / K, k = idx - n * K;
    WT[idx] = f2h_bits(W[(size_t)k * N + n]);
}

// ---------------- f16 MFMA GEMM: C[M,N] = A[M,K] @ Bt[N,K]^T ----------------
template<int KDIM>
__global__ __launch_bounds__(256) void gemm_f16(const ushort* __restrict__ A,
                                                const ushort* __restrict__ Bt,
                                                ushort* __restrict__ C,
                                                int M, int N) {
    __shared__ __align__(16) ushort Asl[128 * 64];
    __shared__ __align__(16) ushort Bsl[128 * 64];
    const int tid  = threadIdx.x;
    const int lane = tid & 63;
    const int wid  = tid >> 6;
    const int wr   = wid >> 1, wc = wid & 1;
    const int fr   = lane & 15, fq = lane >> 4;
    const int m0   = blockIdx.x * 128;
    const int n0   = blockIdx.y * 128;

    f32x4 acc[4][4] = {};

    for (int k0 = 0; k0 < KDIM; k0 += 64) {
        __syncthreads();
        #pragma unroll
        for (int i = 0; i < 4; ++i) {
            int chunk = wid * 4 + i;
            int r = chunk * 8 + (lane >> 3);
            const ushort* ga = A  + (size_t)(m0 + r) * KDIM + k0 + (lane & 7) * 8;
            const ushort* gb = Bt + (size_t)(n0 + r) * KDIM + k0 + (lane & 7) * 8;
            __builtin_amdgcn_global_load_lds(
                (const __attribute__((address_space(1))) void*)ga,
                (__attribute__((address_space(3))) void*)(Asl + chunk * 512), 16, 0, 0);
            __builtin_amdgcn_global_load_lds(
                (const __attribute__((address_space(1))) void*)gb,
                (__attribute__((address_space(3))) void*)(Bsl + chunk * 512), 16, 0, 0);
        }
        __syncthreads();
        #pragma unroll
        for (int ks = 0; ks < 2; ++ks) {
            short8 a[4], b[4];
            #pragma unroll
            for (int m = 0; m < 4; ++m)
                a[m] = *(const short8*)&Asl[(wr * 64 + m * 16 + fr) * 64 + ks * 32 + fq * 8];
            #pragma unroll
            for (int n = 0; n < 4; ++n)
                b[n] = *(const short8*)&Bsl[(wc * 64 + n * 16 + fr) * 64 + ks * 32 + fq * 8];
            #pragma unroll
            for (int m = 0; m < 4; ++m)
                #pragma unroll
                for (int n = 0; n < 4; ++n)
                    acc[m][n] = __builtin_amdgcn_mfma_f32_16x16x32_f16(
                        __builtin_bit_cast(half8v, a[m]),
                        __builtin_bit_cast(half8v, b[n]), acc[m][n], 0, 0, 0);
        }
    }
    #pragma unroll
    for (int m = 0; m < 4; ++m) {
        #pragma unroll
        for (int r = 0; r < 4; ++r) {
            int row = m0 + wr * 64 + m * 16 + fq * 4 + r;
            if (row >= M) continue;
            #pragma unroll
            for (int n = 0; n < 4; ++n)
                C[(size_t)row * N + n0 + wc * 64 + n * 16 + fr] = f2h_bits(acc[m][n][r]);
        }
    }
}

// ---------------- attention dot products ----------------
__global__ void dots1(const ushort* __restrict__ h1, const float* __restrict__ a_src,
                      const float* __restrict__ a_dst,
                      float* __restrict__ es, float* __restrict__ ed) {
    int gw   = (blockIdx.x * blockDim.x + threadIdx.x) >> 6;
    int lane = threadIdx.x & 63;
    if (gw >= NNODES) return;
    short8 v = *(const short8*)&h1[(size_t)gw * D1 + lane * 8];
    half8v hv = __builtin_bit_cast(half8v, v);
    int h = lane >> 3, c0 = (lane & 7) * 8;
    float s = 0.f, d = 0.f;
    #pragma unroll
    for (int j = 0; j < 8; ++j) {
        float x = (float)hv[j];
        s += x * a_src[h * HID + c0 + j];
        d += x * a_dst[h * HID + c0 + j];
    }
    #pragma unroll
    for (int off = 1; off < 8; off <<= 1) {
        s += __shfl_xor(s, off);
        d += __shfl_xor(d, off);
    }
    if ((lane & 7) == 0) { es[gw * NH + h] = s; ed[gw * NH + h] = d; }
}

__global__ void dots2(const ushort* __restrict__ h2, const float* __restrict__ a_src,
                      const float* __restrict__ a_dst,
                      float* __restrict__ es, float* __restrict__ ed) {
    int gw   = (blockIdx.x * blockDim.x + threadIdx.x) >> 6;
    int lane = threadIdx.x & 63;
    if (gw >= NNODES) return;
    uint u = *(const uint*)&h2[(size_t)gw * OUTC + lane * 2];
    float x0 = h2f((ushort)(u & 0xffffu)), x1 = h2f((ushort)(u >> 16));
    float s = x0 * a_src[lane * 2] + x1 * a_src[lane * 2 + 1];
    float d = x0 * a_dst[lane * 2] + x1 * a_dst[lane * 2 + 1];
    #pragma unroll
    for (int off = 1; off < 64; off <<= 1) {
        s += __shfl_xor(s, off);
        d += __shfl_xor(d, off);
    }
    if (lane == 0) { es[gw] = s; ed[gw] = d; }
}

// ---------------- layer-1 aggregation ----------------
// 256 thr = 4 waves per block, 2 nodes/block (2 waves each).
// Softmax: wave handles 4 heads (float4 esrc loads, shfl reduce).
// Gather: thread owns 4 channels; dwordx2 loads + v_pk_fma_f16 (alpha packed half2).
#define CAP1 128
__global__ __launch_bounds__(256) void attn1(const ushort* __restrict__ h1,
                                             const float* __restrict__ esrc,
                                             const float* __restrict__ edst,
                                             const int* __restrict__ rs,
                                             const int* __restrict__ csr_src,
                                             const float* __restrict__ b1,
                                             ushort* __restrict__ out1) {
    int t = threadIdx.x;
    int lane = t & 63, wid = t >> 6;
    int nidx = wid >> 1, wv = wid & 1;
    int n = blockIdx.x * 2 + nidx;
    int beg = rs[n], deg = rs[n + 1] - beg;
    int dcap = min(deg, CAP1);
    __shared__ float alpha_sh[2][CAP1][NH];   // 8 KB; pass1 f32 v, pass2 packed half2
    __shared__ int   ssrc_sh[2][CAP1];
    __shared__ float msh[2][NH], rinv_sh[2][NH];

    // stage src indices (waves of the pair cover e = 0..127 stride 128)
    {
        int e0 = t & 127;
        for (int e = e0; e < dcap; e += 128) ssrc_sh[nidx][e] = csr_src[beg + e];
    }
    __syncthreads();

    // softmax: this wave owns heads h0..h0+3
    {
        int h0 = wv * 4;
        float4 ed4 = *(const float4*)&edst[n * NH + h0];
        float m0 = -1e30f, m1 = -1e30f, m2 = -1e30f, m3 = -1e30f;
        for (int e = lane; e < deg; e += 64) {
            int s = (e < CAP1) ? ssrc_sh[nidx][e] : csr_src[beg + e];
            float4 es4 = *(const float4*)&esrc[s * NH + h0];
            float v0 = leaky(es4.x + ed4.x), v1 = leaky(es4.y + ed4.y);
            float v2 = leaky(es4.z + ed4.z), v3 = leaky(es4.w + ed4.w);
            if (e < CAP1) {
                float4 vv = { v0, v1, v2, v3 };
                *(float4*)&alpha_sh[nidx][e][h0] = vv;
            }
            m0 = fmaxf(m0, v0); m1 = fmaxf(m1, v1);
            m2 = fmaxf(m2, v2); m3 = fmaxf(m3, v3);
        }
        #pragma unroll
        for (int off = 32; off; off >>= 1) {
            m0 = fmaxf(m0, __shfl_xor(m0, off));
            m1 = fmaxf(m1, __shfl_xor(m1, off));
            m2 = fmaxf(m2, __shfl_xor(m2, off));
            m3 = fmaxf(m3, __shfl_xor(m3, off));
        }
        float s0 = 0.f, s1 = 0.f, s2 = 0.f, s3 = 0.f;
        for (int e = lane; e < deg; e += 64) {
            float v0, v1, v2, v3;
            if (e < CAP1) {
                float4 vv = *(const float4*)&alpha_sh[nidx][e][h0];
                v0 = vv.x; v1 = vv.y; v2 = vv.z; v3 = vv.w;
            } else {
                int s = csr_src[beg + e];
                float4 es4 = *(const float4*)&esrc[s * NH + h0];
                v0 = leaky(es4.x + ed4.x); v1 = leaky(es4.y + ed4.y);
                v2 = leaky(es4.z + ed4.z); v3 = leaky(es4.w + ed4.w);
            }
            float p0 = __expf(v0 - m0), p1 = __expf(v1 - m1);
            float p2 = __expf(v2 - m2), p3 = __expf(v3 - m3);
            if (e < CAP1) {
                uint4 pk = { splat_h2(p0), splat_h2(p1), splat_h2(p2), splat_h2(p3) };
                *(uint4*)&alpha_sh[nidx][e][h0] = pk;
            }
            s0 += p0; s1 += p1; s2 += p2; s3 += p3;
        }
        #pragma unroll
        for (int off = 32; off; off >>= 1) {
            s0 += __shfl_xor(s0, off); s1 += __shfl_xor(s1, off);
            s2 += __shfl_xor(s2, off); s3 += __shfl_xor(s3, off);
        }
        if (lane == 0) {
            msh[nidx][h0] = m0; msh[nidx][h0 + 1] = m1;
            msh[nidx][h0 + 2] = m2; msh[nidx][h0 + 3] = m3;
            rinv_sh[nidx][h0]     = 1.f / (s0 + 1e-16f);
            rinv_sh[nidx][h0 + 1] = 1.f / (s1 + 1e-16f);
            rinv_sh[nidx][h0 + 2] = 1.f / (s2 + 1e-16f);
            rinv_sh[nidx][h0 + 3] = 1.f / (s3 + 1e-16f);
        }
    }
    __syncthreads();

    // gather: tt = t&127 owns channels 4tt..4tt+3 of node nidx; head h = tt>>4
    int tt = t & 127;
    int c0 = tt * 4;
    int h = tt >> 4;
    float m = msh[nidx][h], ri = rinv_sh[nidx][h];
    float edn = edst[n * NH + h];
    half2v a01 = {}, a01b = {}, a23 = {}, a23b = {};
    const int* ss = ssrc_sh[nidx];
    int e = 0;
    for (; e + 4 <= dcap; e += 4) {
        int s0i = ss[e], s1i = ss[e + 1], s2i = ss[e + 2], s3i = ss[e + 3];
        uint2 u0 = *(const uint2*)&h1[(size_t)s0i * D1 + c0];
        uint2 u1 = *(const uint2*)&h1[(size_t)s1i * D1 + c0];
        uint2 u2 = *(const uint2*)&h1[(size_t)s2i * D1 + c0];
        uint2 u3 = *(const uint2*)&h1[(size_t)s3i * D1 + c0];
        half2v p0 = as_h2(*(const uint*)&alpha_sh[nidx][e][h]);
        half2v p1 = as_h2(*(const uint*)&alpha_sh[nidx][e + 1][h]);
        half2v p2 = as_h2(*(const uint*)&alpha_sh[nidx][e + 2][h]);
        half2v p3 = as_h2(*(const uint*)&alpha_sh[nidx][e + 3][h]);
        a01  = as_h2(u0.x) * p0 + a01;  a23  = as_h2(u0.y) * p0 + a23;
        a01b = as_h2(u1.x) * p1 + a01b; a23b = as_h2(u1.y) * p1 + a23b;
        a01  = as_h2(u2.x) * p2 + a01;  a23  = as_h2(u2.y) * p2 + a23;
        a01b = as_h2(u3.x) * p3 + a01b; a23b = as_h2(u3.y) * p3 + a23b;
    }
    for (; e < dcap; ++e) {
        int s = ss[e];
        uint2 u = *(const uint2*)&h1[(size_t)s * D1 + c0];
        half2v p = as_h2(*(const uint*)&alpha_sh[nidx][e][h]);
        a01 = as_h2(u.x) * p + a01;
        a23 = as_h2(u.y) * p + a23;
    }
    for (; e < deg; ++e) {   // overflow (deg > CAP1): recompute alpha
        int s = csr_src[beg + e];
        float p = __expf(leaky(esrc[s * NH + h] + edn) - m);
        half2v ph = as_h2(splat_h2(p));
        uint2 u = *(const uint2*)&h1[(size_t)s * D1 + c0];
        a01 = as_h2(u.x) * ph + a01;
        a23 = as_h2(u.y) * ph + a23;
    }
    float ac0 = (float)a01[0] + (float)a01b[0];
    float ac1 = (float)a01[1] + (float)a01b[1];
    float ac2 = (float)a23[0] + (float)a23b[0];
    float ac3 = (float)a23[1] + (float)a23b[1];
    float4 bb = *(const float4*)&b1[c0];
    float o0 = fmaxf(ac0 * ri + bb.x, 0.f);
    float o1 = fmaxf(ac1 * ri + bb.y, 0.f);
    float o2 = fmaxf(ac2 * ri + bb.z, 0.f);
    float o3 = fmaxf(ac3 * ri + bb.w, 0.f);
    uint2 pkout;
    pkout.x = (uint)f2h_bits(o0) | ((uint)f2h_bits(o1) << 16);
    pkout.y = (uint)f2h_bits(o2) | ((uint)f2h_bits(o3) << 16);
    *(uint2*)&out1[(size_t)n * D1 + c0] = pkout;
}

// ---------------- layer-2 aggregation ----------------
// 8 nodes per 256-block; 32 lanes per node; thread owns 4 channels.
#define CAP2 128
__global__ __launch_bounds__(256) void attn2(const ushort* __restrict__ h2,
                                             const float* __restrict__ esrc,
                                             const float* __restrict__ edst,
                                             const int* __restrict__ rs,
                                             const int* __restrict__ csr_src,
                                             const float* __restrict__ b2,
                                             float* __restrict__ out) {
    int t = threadIdx.x;
    int g = t >> 5, lane32 = t & 31;
    int n = blockIdx.x * 8 + g;
    if (n >= NNODES) return;
    int beg = rs[n], deg = rs[n + 1] - beg;
    int dcap = min(deg, CAP2);
    __shared__ float al_sh[8][CAP2];
    __shared__ int   ss_sh[8][CAP2];
    float* al = al_sh[g];
    int*   ss = ss_sh[g];

    for (int e = lane32; e < dcap; e += 32) ss[e] = csr_src[beg + e];
    // same 32-lane group reads its own writes — intra-wave, no barrier needed

    float edn = edst[n];
    float m = -1e30f;
    for (int e = lane32; e < deg; e += 32) {
        int s = (e < CAP2) ? ss[e] : csr_src[beg + e];
        float v = leaky(esrc[s] + edn);
        if (e < CAP2) al[e] = v;
        m = fmaxf(m, v);
    }
    #pragma unroll
    for (int off = 16; off; off >>= 1) m = fmaxf(m, __shfl_xor(m, off));
    float ssum = 0.f;
    for (int e = lane32; e < deg; e += 32) {
        float v = (e < CAP2) ? al[e] : leaky(esrc[csr_src[beg + e]] + edn);
        float p = __expf(v - m);
        if (e < CAP2) *(uint*)&al[e] = splat_h2(p);
        ssum += p;
    }
    #pragma unroll
    for (int off = 16; off; off >>= 1) ssum += __shfl_xor(ssum, off);
    float ri = 1.f / (ssum + 1e-16f);

    int c0 = lane32 * 4;
    half2v a01 = {}, a01b = {}, a23 = {}, a23b = {};
    int e = 0;
    for (; e + 4 <= dcap; e += 4) {
        int s0i = ss[e], s1i = ss[e + 1], s2i = ss[e + 2], s3i = ss[e + 3];
        uint2 u0 = *(const uint2*)&h2[(size_t)s0i * OUTC + c0];
        uint2 u1 = *(const uint2*)&h2[(size_t)s1i * OUTC + c0];
        uint2 u2 = *(const uint2*)&h2[(size_t)s2i * OUTC + c0];
        uint2 u3 = *(const uint2*)&h2[(size_t)s3i * OUTC + c0];
        half2v p0 = as_h2(*(const uint*)&al[e]);
        half2v p1 = as_h2(*(const uint*)&al[e + 1]);
        half2v p2 = as_h2(*(const uint*)&al[e + 2]);
        half2v p3 = as_h2(*(const uint*)&al[e + 3]);
        a01  = as_h2(u0.x) * p0 + a01;  a23  = as_h2(u0.y) * p0 + a23;
        a01b = as_h2(u1.x) * p1 + a01b; a23b = as_h2(u1.y) * p1 + a23b;
        a01  = as_h2(u2.x) * p2 + a01;  a23  = as_h2(u2.y) * p2 + a23;
        a01b = as_h2(u3.x) * p3 + a01b; a23b = as_h2(u3.y) * p3 + a23b;
    }
    for (; e < dcap; ++e) {
        int s = ss[e];
        uint2 u = *(const uint2*)&h2[(size_t)s * OUTC + c0];
        half2v p = as_h2(*(const uint*)&al[e]);
        a01 = as_h2(u.x) * p + a01;
        a23 = as_h2(u.y) * p + a23;
    }
    for (; e < deg; ++e) {
        int s = csr_src[beg + e];
        float p = __expf(leaky(esrc[s] + edn) - m);
        half2v ph = as_h2(splat_h2(p));
        uint2 u = *(const uint2*)&h2[(size_t)s * OUTC + c0];
        a01 = as_h2(u.x) * ph + a01;
        a23 = as_h2(u.y) * ph + a23;
    }
    float4 bb = *(const float4*)&b2[c0];
    float4 o;
    o.x = ((float)a01[0] + (float)a01b[0]) * ri + bb.x;
    o.y = ((float)a01[1] + (float)a01b[1]) * ri + bb.y;
    o.z = ((float)a23[0] + (float)a23b[0]) * ri + bb.z;
    o.w = ((float)a23[1] + (float)a23b[1]) * ri + bb.w;
    *(float4*)&out[(size_t)n * OUTC + c0] = o;
}

// ---------------- launch ----------------
extern "C" void kernel_launch(void* const* d_in, const int* in_sizes, int n_in,
                              void* d_out, int out_size, void* d_ws, size_t ws_size,
                              hipStream_t stream) {
    const float* x   = (const float*)d_in[0];
    const int*   ei  = (const int*)  d_in[1];
    const float* W1  = (const float*)d_in[2];
    const float* b1  = (const float*)d_in[3];
    const float* as1 = (const float*)d_in[4];
    const float* ad1 = (const float*)d_in[5];
    const float* W2  = (const float*)d_in[6];
    const float* b2  = (const float*)d_in[7];
    const float* as2 = (const float*)d_in[8];
    const float* ad2 = (const float*)d_in[9];
    float* out = (float*)d_out;

    char* ws = (char*)d_ws;
    size_t off = 0;
    auto alloc = [&](size_t bytes) -> void* {
        void* p = ws + off;
        off = (off + bytes + 255) & ~(size_t)255;
        return p;
    };
    ushort* xh    = (ushort*)alloc((size_t)MPAD * INC * 2);
    ushort* w1t   = (ushort*)alloc((size_t)D1 * INC * 2);
    ushort* w2t   = (ushort*)alloc((size_t)OUTC * D1 * 2);
    ushort* h1h   = (ushort*)alloc((size_t)MPAD * D1 * 2);
    ushort* out1h = (ushort*)alloc((size_t)MPAD * D1 * 2);
    ushort* h2h   = (ushort*)alloc((size_t)MPAD * OUTC * 2);
    float*  es1   = (float*)alloc((size_t)NNODES * NH * 4);
    float*  ed1   = (float*)alloc((size_t)NNODES * NH * 4);
    float*  es2   = (float*)alloc((size_t)NNODES * 4);
    float*  ed2   = (float*)alloc((size_t)NNODES * 4);
    int*    deg   = (int*)alloc((size_t)NNODES * 4);
    int*    rs    = (int*)alloc((size_t)(NNODES + 1) * 4);
    int*    cur   = (int*)alloc((size_t)NNODES * 4);
    int*    csr   = (int*)alloc((size_t)ETOT * 4);

    // CSR build
    hipMemsetAsync(deg, 0, (size_t)NNODES * 4, stream);
    count_deg<<<(ETOT + 255) / 256, 256, 0, stream>>>(ei, deg);
    scan_deg<<<1, 1024, 0, stream>>>(deg, rs);
    hipMemcpyAsync(cur, rs, (size_t)NNODES * 4, hipMemcpyDeviceToDevice, stream);
    scatter_edges<<<(ETOT + 255) / 256, 256, 0, stream>>>(ei, cur, csr);

    // dtype prep
    cast_f16<<<(NNODES * INC / 4 + 255) / 256, 256, 0, stream>>>(x, xh, NNODES * INC / 4);
    cast_wT<<<(INC * D1 + 255) / 256, 256, 0, stream>>>(W1, w1t, INC, D1);
    cast_wT<<<(D1 * OUTC + 255) / 256, 256, 0, stream>>>(W2, w2t, D1, OUTC);

    // layer 1
    gemm_f16<INC><<<dim3(MPAD / 128, D1 / 128), 256, 0, stream>>>(xh, w1t, h1h, NNODES, D1);
    dots1<<<(NNODES * 64 + 255) / 256, 256, 0, stream>>>(h1h, as1, ad1, es1, ed1);
    attn1<<<NNODES / 2, 256, 0, stream>>>(h1h, es1, ed1, rs, csr, b1, out1h);

    // layer 2
    gemm_f16<D1><<<dim3(MPAD / 128, OUTC / 128), 256, 0, stream>>>(out1h, w2t, h2h, NNODES, OUTC);
    dots2<<<(NNODES * 64 + 255) / 256, 256, 0, stream>>>(h2h, as2, ad2, es2, ed2);
    attn2<<<NNODES / 8, 256, 0, stream>>>(h2h, es2, ed2, rs, csr, b2, out);
}

// Round 7
// 590.128 us; speedup vs baseline: 2.1234x; 1.0018x over previous
//
#include <hip/hip_runtime.h>
#include <hip/hip_fp16.h>

#define NNODES 50000
#define NEDGES 800000
#define ETOT   (NNODES + NEDGES)   // 850000 edges incl. self-loops
#define NH     8
#define HID    64
#define D1     512                  // NH*HID
#define INC    512
#define OUTC   128
#define NEG    0.2f
#define MPAD   50048                // 391*128, padded row count for GEMM tiles

typedef __attribute__((ext_vector_type(8))) short short8;
typedef __attribute__((ext_vector_type(4))) float f32x4;
typedef _Float16 half8v __attribute__((ext_vector_type(8)));
typedef _Float16 half2v __attribute__((ext_vector_type(2)));

__device__ __forceinline__ ushort f2h_bits(float x) {
    _Float16 h = (_Float16)x; return __builtin_bit_cast(ushort, h);
}
__device__ __forceinline__ float h2f(ushort b) {
    return (float)__builtin_bit_cast(_Float16, b);
}
__device__ __forceinline__ uint splat_h2(float p) {
    uint b = (uint)f2h_bits(p); return b | (b << 16);
}
__device__ __forceinline__ half2v as_h2(uint u) { return __builtin_bit_cast(half2v, u); }
__device__ __forceinline__ float leaky(float v) { return v >= 0.f ? v : NEG * v; }

// ---------------- CSR build ----------------
__global__ void count_deg(const int* __restrict__ ei, int* __restrict__ deg) {
    int i = blockIdx.x * 256 + threadIdx.x;
    if (i >= ETOT) return;
    int dst = (i < NEDGES) ? ei[NEDGES + i] : (i - NEDGES);
    atomicAdd(&deg[dst], 1);
}

__global__ void scan_deg(const int* __restrict__ deg, int* __restrict__ rs) {
    __shared__ int part[1024];
    const int n = NNODES;
    const int CH = (n + 1023) / 1024;
    int t = threadIdx.x;
    int lo = t * CH, hi = min(lo + CH, n);
    int s = 0;
    for (int i = lo; i < hi; ++i) s += deg[i];
    part[t] = s;
    __syncthreads();
    for (int off = 1; off < 1024; off <<= 1) {
        int v = (t >= off) ? part[t - off] : 0;
        __syncthreads();
        part[t] += v;
        __syncthreads();
    }
    int run = (t == 0) ? 0 : part[t - 1];
    for (int i = lo; i < hi; ++i) { rs[i] = run; run += deg[i]; }
    if (hi == n) rs[n] = run;
}

__global__ void scatter_edges(const int* __restrict__ ei, int* __restrict__ cursor,
                              int* __restrict__ csr_src) {
    int i = blockIdx.x * 256 + threadIdx.x;
    if (i >= ETOT) return;
    int src, dst;
    if (i < NEDGES) { src = ei[i]; dst = ei[NEDGES + i]; }
    else            { src = dst = i - NEDGES; }
    int pos = atomicAdd(&cursor[dst], 1);
    csr_src[pos] = src;
}

// ---------------- dtype prep (f16) ----------------
__global__ void cast_f16(const float* __restrict__ x, ushort* __restrict__ xh, int n4) {
    int i = blockIdx.x * 256 + threadIdx.x;
    if (i >= n4) return;
    float4 v = *(const float4*)&x[(size_t)i * 4];
    ushort4 o = { f2h_bits(v.x), f2h_bits(v.y), f2h_bits(v.z), f2h_bits(v.w) };
    *(ushort4*)&xh[(size_t)i * 4] = o;
}

// WT[n][k] = W[k][n], f16 out.
__global__ void cast_wT(const float* __restrict__ W, ushort* __restrict__ WT, int K, int N) {
    int idx = blockIdx.x * 256 + threadIdx.x;
    if (idx >= K * N) return;
    int n = idx / K, k = idx - n * K;
    WT[idx] = f2h_bits(W[(size_t)k * N + n]);
}

// ---------------- f16 MFMA GEMM: C[M,N] = A[M,K] @ Bt[N,K]^T ----------------
// 128x128 tile, BK=64. T2 swizzle per rule #21: linear gload_lds dest +
// inverse-swizzled GLOBAL source column + swizzled ds_read slot.
// LDS[row][slot16] holds G(row, slot16 ^ (row&7)); read slot' = slot ^ (row&7).
template<int KDIM>
__global__ __launch_bounds__(256) void gemm_f16(const ushort* __restrict__ A,
                                                const ushort* __restrict__ Bt,
                                                ushort* __restrict__ C,
                                                int M, int N) {
    __shared__ __align__(16) ushort Asl[128 * 64];
    __shared__ __align__(16) ushort Bsl[128 * 64];
    const int tid  = threadIdx.x;
    const int lane = tid & 63;
    const int wid  = tid >> 6;
    const int wr   = wid >> 1, wc = wid & 1;
    const int fr   = lane & 15, fq = lane >> 4;
    const int m0   = blockIdx.x * 128;
    const int n0   = blockIdx.y * 128;

    f32x4 acc[4][4] = {};

    // staging source column: slot = lane&7 in LDS; fetch global slot^(row&7), row&7=(lane>>3)&7
    const int gcol = (((lane & 7) ^ ((lane >> 3) & 7))) * 8;

    for (int k0 = 0; k0 < KDIM; k0 += 64) {
        __syncthreads();
        #pragma unroll
        for (int i = 0; i < 4; ++i) {
            int chunk = wid * 4 + i;
            int r = chunk * 8 + (lane >> 3);
            const ushort* ga = A  + (size_t)(m0 + r) * KDIM + k0 + gcol;
            const ushort* gb = Bt + (size_t)(n0 + r) * KDIM + k0 + gcol;
            __builtin_amdgcn_global_load_lds(
                (const __attribute__((address_space(1))) void*)ga,
                (__attribute__((address_space(3))) void*)(Asl + chunk * 512), 16, 0, 0);
            __builtin_amdgcn_global_load_lds(
                (const __attribute__((address_space(1))) void*)gb,
                (__attribute__((address_space(3))) void*)(Bsl + chunk * 512), 16, 0, 0);
        }
        __syncthreads();
        #pragma unroll
        for (int ks = 0; ks < 2; ++ks) {
            short8 a[4], b[4];
            #pragma unroll
            for (int m = 0; m < 4; ++m) {
                int row = wr * 64 + m * 16 + fr;
                int slot = (ks * 4 + fq) ^ (fr & 7);
                a[m] = *(const short8*)&Asl[row * 64 + slot * 8];
            }
            #pragma unroll
            for (int n = 0; n < 4; ++n) {
                int row = wc * 64 + n * 16 + fr;
                int slot = (ks * 4 + fq) ^ (fr & 7);
                b[n] = *(const short8*)&Bsl[row * 64 + slot * 8];
            }
            #pragma unroll
            for (int m = 0; m < 4; ++m)
                #pragma unroll
                for (int n = 0; n < 4; ++n)
                    acc[m][n] = __builtin_amdgcn_mfma_f32_16x16x32_f16(
                        __builtin_bit_cast(half8v, a[m]),
                        __builtin_bit_cast(half8v, b[n]), acc[m][n], 0, 0, 0);
        }
    }
    #pragma unroll
    for (int m = 0; m < 4; ++m) {
        #pragma unroll
        for (int r = 0; r < 4; ++r) {
            int row = m0 + wr * 64 + m * 16 + fq * 4 + r;
            if (row >= M) continue;
            #pragma unroll
            for (int n = 0; n < 4; ++n)
                C[(size_t)row * N + n0 + wc * 64 + n * 16 + fr] = f2h_bits(acc[m][n][r]);
        }
    }
}

// ---------------- attention dot products ----------------
__global__ void dots1(const ushort* __restrict__ h1, const float* __restrict__ a_src,
                      const float* __restrict__ a_dst,
                      float* __restrict__ es, float* __restrict__ ed) {
    int gw   = (blockIdx.x * blockDim.x + threadIdx.x) >> 6;
    int lane = threadIdx.x & 63;
    if (gw >= NNODES) return;
    short8 v = *(const short8*)&h1[(size_t)gw * D1 + lane * 8];
    half8v hv = __builtin_bit_cast(half8v, v);
    int h = lane >> 3, c0 = (lane & 7) * 8;
    float s = 0.f, d = 0.f;
    #pragma unroll
    for (int j = 0; j < 8; ++j) {
        float x = (float)hv[j];
        s += x * a_src[h * HID + c0 + j];
        d += x * a_dst[h * HID + c0 + j];
    }
    #pragma unroll
    for (int off = 1; off < 8; off <<= 1) {
        s += __shfl_xor(s, off);
        d += __shfl_xor(d, off);
    }
    if ((lane & 7) == 0) { es[gw * NH + h] = s; ed[gw * NH + h] = d; }
}

__global__ void dots2(const ushort* __restrict__ h2, const float* __restrict__ a_src,
                      const float* __restrict__ a_dst,
                      float* __restrict__ es, float* __restrict__ ed) {
    int gw   = (blockIdx.x * blockDim.x + threadIdx.x) >> 6;
    int lane = threadIdx.x & 63;
    if (gw >= NNODES) return;
    uint u = *(const uint*)&h2[(size_t)gw * OUTC + lane * 2];
    float x0 = h2f((ushort)(u & 0xffffu)), x1 = h2f((ushort)(u >> 16));
    float s = x0 * a_src[lane * 2] + x1 * a_src[lane * 2 + 1];
    float d = x0 * a_dst[lane * 2] + x1 * a_dst[lane * 2 + 1];
    #pragma unroll
    for (int off = 1; off < 64; off <<= 1) {
        s += __shfl_xor(s, off);
        d += __shfl_xor(d, off);
    }
    if (lane == 0) { es[gw] = s; ed[gw] = d; }
}

// ---------------- layer-1 aggregation ----------------
// 1 wave per node, 4 nodes per 256-block, NO block barriers (wave-private LDS).
// Softmax: each lane processes one edge x all 8 heads; named-scalar shfl reduce.
// Gather: lane owns 8 channels (dwordx4 = 16B), head = lane>>3; alpha in pad-9 LDS.
#define CAP1 128
__global__ __launch_bounds__(256) void attn1(const ushort* __restrict__ h1,
                                             const float* __restrict__ esrc,
                                             const float* __restrict__ edst,
                                             const int* __restrict__ rs,
                                             const int* __restrict__ csr_src,
                                             const float* __restrict__ b1,
                                             ushort* __restrict__ out1) {
    int t = threadIdx.x, lane = t & 63, w = t >> 6;
    int n = blockIdx.x * 4 + w;
    int beg = rs[n], deg = rs[n + 1] - beg;
    int dcap = min(deg, CAP1);
    __shared__ uint  alpha_sh[4][CAP1][9];   // pad 9: conflict-free e-stride
    __shared__ int   ssrc_sh[4][CAP1];
    uint (*alpha)[9] = alpha_sh[w];
    int* ss = ssrc_sh[w];

    for (int e = lane; e < dcap; e += 64) ss[e] = csr_src[beg + e];

    float4 edA = *(const float4*)&edst[n * NH];
    float4 edB = *(const float4*)&edst[n * NH + 4];
    float mx[8], sm[8];
    #pragma unroll
    for (int h = 0; h < 8; ++h) { mx[h] = -1e30f; sm[h] = 0.f; }

    // pass 1: v, per-lane max (store v bits in alpha)
    for (int e = lane; e < deg; e += 64) {
        int s = (e < CAP1) ? ss[e] : csr_src[beg + e];
        float4 eA = *(const float4*)&esrc[(size_t)s * NH];
        float4 eB = *(const float4*)&esrc[(size_t)s * NH + 4];
        float v[8] = { leaky(eA.x + edA.x), leaky(eA.y + edA.y),
                       leaky(eA.z + edA.z), leaky(eA.w + edA.w),
                       leaky(eB.x + edB.x), leaky(eB.y + edB.y),
                       leaky(eB.z + edB.z), leaky(eB.w + edB.w) };
        #pragma unroll
        for (int h = 0; h < 8; ++h) {
            if (e < CAP1) alpha[e][h] = __float_as_uint(v[h]);
            mx[h] = fmaxf(mx[h], v[h]);
        }
    }
    #pragma unroll
    for (int off = 1; off < 64; off <<= 1)
        #pragma unroll
        for (int h = 0; h < 8; ++h)
            mx[h] = fmaxf(mx[h], __shfl_xor(mx[h], off));

    // pass 2: p = exp(v-m) -> alpha (h2 splat), per-lane sum
    for (int e = lane; e < deg; e += 64) {
        float v[8];
        if (e < CAP1) {
            #pragma unroll
            for (int h = 0; h < 8; ++h) v[h] = __uint_as_float(alpha[e][h]);
        } else {
            int s = csr_src[beg + e];
            float4 eA = *(const float4*)&esrc[(size_t)s * NH];
            float4 eB = *(const float4*)&esrc[(size_t)s * NH + 4];
            v[0] = leaky(eA.x + edA.x); v[1] = leaky(eA.y + edA.y);
            v[2] = leaky(eA.z + edA.z); v[3] = leaky(eA.w + edA.w);
            v[4] = leaky(eB.x + edB.x); v[5] = leaky(eB.y + edB.y);
            v[6] = leaky(eB.z + edB.z); v[7] = leaky(eB.w + edB.w);
        }
        #pragma unroll
        for (int h = 0; h < 8; ++h) {
            float p = __expf(v[h] - mx[h]);
            if (e < CAP1) alpha[e][h] = splat_h2(p);
            sm[h] += p;
        }
    }
    #pragma unroll
    for (int off = 1; off < 64; off <<= 1)
        #pragma unroll
        for (int h = 0; h < 8; ++h)
            sm[h] += __shfl_xor(sm[h], off);

    // per-lane head select via constant-indexed unroll (no dynamic reg index)
    int h = lane >> 3;
    float mm = mx[0], ssv = sm[0], edn = edA.x;
    float edv[8] = { edA.x, edA.y, edA.z, edA.w, edB.x, edB.y, edB.z, edB.w };
    #pragma unroll
    for (int hh = 1; hh < 8; ++hh)
        if (h == hh) { mm = mx[hh]; ssv = sm[hh]; edn = edv[hh]; }
    float ri = 1.f / (ssv + 1e-16f);

    // gather: lane owns channels c0..c0+7
    int c0 = lane * 8;
    half2v aA0 = {}, aA1 = {}, aA2 = {}, aA3 = {};
    half2v aB0 = {}, aB1 = {}, aB2 = {}, aB3 = {};
    int e = 0;
    for (; e + 2 <= dcap; e += 2) {
        int s0i = ss[e], s1i = ss[e + 1];
        uint4 u0 = *(const uint4*)&h1[(size_t)s0i * D1 + c0];
        uint4 u1 = *(const uint4*)&h1[(size_t)s1i * D1 + c0];
        half2v p0 = as_h2(alpha[e][h]);
        half2v p1 = as_h2(alpha[e + 1][h]);
        aA0 = as_h2(u0.x) * p0 + aA0; aA1 = as_h2(u0.y) * p0 + aA1;
        aA2 = as_h2(u0.z) * p0 + aA2; aA3 = as_h2(u0.w) * p0 + aA3;
        aB0 = as_h2(u1.x) * p1 + aB0; aB1 = as_h2(u1.y) * p1 + aB1;
        aB2 = as_h2(u1.z) * p1 + aB2; aB3 = as_h2(u1.w) * p1 + aB3;
    }
    for (; e < dcap; ++e) {
        int s = ss[e];
        uint4 u = *(const uint4*)&h1[(size_t)s * D1 + c0];
        half2v p = as_h2(alpha[e][h]);
        aA0 = as_h2(u.x) * p + aA0; aA1 = as_h2(u.y) * p + aA1;
        aA2 = as_h2(u.z) * p + aA2; aA3 = as_h2(u.w) * p + aA3;
    }
    for (; e < deg; ++e) {   // overflow (deg > CAP1)
        int s = csr_src[beg + e];
        float p = __expf(leaky(esrc[(size_t)s * NH + h] + edn) - mm);
        half2v ph = as_h2(splat_h2(p));
        uint4 u = *(const uint4*)&h1[(size_t)s * D1 + c0];
        aA0 = as_h2(u.x) * ph + aA0; aA1 = as_h2(u.y) * ph + aA1;
        aA2 = as_h2(u.z) * ph + aA2; aA3 = as_h2(u.w) * ph + aA3;
    }
    float4 bb0 = *(const float4*)&b1[c0];
    float4 bb1 = *(const float4*)&b1[c0 + 4];
    float o0 = fmaxf(((float)aA0[0] + (float)aB0[0]) * ri + bb0.x, 0.f);
    float o1 = fmaxf(((float)aA0[1] + (float)aB0[1]) * ri + bb0.y, 0.f);
    float o2 = fmaxf(((float)aA1[0] + (float)aB1[0]) * ri + bb0.z, 0.f);
    float o3 = fmaxf(((float)aA1[1] + (float)aB1[1]) * ri + bb0.w, 0.f);
    float o4 = fmaxf(((float)aA2[0] + (float)aB2[0]) * ri + bb1.x, 0.f);
    float o5 = fmaxf(((float)aA2[1] + (float)aB2[1]) * ri + bb1.y, 0.f);
    float o6 = fmaxf(((float)aA3[0] + (float)aB3[0]) * ri + bb1.z, 0.f);
    float o7 = fmaxf(((float)aA3[1] + (float)aB3[1]) * ri + bb1.w, 0.f);
    uint4 pk;
    pk.x = (uint)f2h_bits(o0) | ((uint)f2h_bits(o1) << 16);
    pk.y = (uint)f2h_bits(o2) | ((uint)f2h_bits(o3) << 16);
    pk.z = (uint)f2h_bits(o4) | ((uint)f2h_bits(o5) << 16);
    pk.w = (uint)f2h_bits(o6) | ((uint)f2h_bits(o7) << 16);
    *(uint4*)&out1[(size_t)n * D1 + c0] = pk;
}

// ---------------- layer-2 aggregation ----------------
// 8 nodes per 256-block; 32 lanes per node; thread owns 4 channels.
#define CAP2 128
__global__ __launch_bounds__(256) void attn2(const ushort* __restrict__ h2,
                                             const float* __restrict__ esrc,
                                             const float* __restrict__ edst,
                                             const int* __restrict__ rs,
                                             const int* __restrict__ csr_src,
                                             const float* __restrict__ b2,
                                             float* __restrict__ out) {
    int t = threadIdx.x;
    int g = t >> 5, lane32 = t & 31;
    int n = blockIdx.x * 8 + g;
    if (n >= NNODES) return;
    int beg = rs[n], deg = rs[n + 1] - beg;
    int dcap = min(deg, CAP2);
    __shared__ float al_sh[8][CAP2];
    __shared__ int   ss_sh[8][CAP2];
    float* al = al_sh[g];
    int*   ss = ss_sh[g];

    for (int e = lane32; e < dcap; e += 32) ss[e] = csr_src[beg + e];

    float edn = edst[n];
    float m = -1e30f;
    for (int e = lane32; e < deg; e += 32) {
        int s = (e < CAP2) ? ss[e] : csr_src[beg + e];
        float v = leaky(esrc[s] + edn);
        if (e < CAP2) al[e] = v;
        m = fmaxf(m, v);
    }
    #pragma unroll
    for (int off = 16; off; off >>= 1) m = fmaxf(m, __shfl_xor(m, off));
    float ssum = 0.f;
    for (int e = lane32; e < deg; e += 32) {
        float v = (e < CAP2) ? al[e] : leaky(esrc[csr_src[beg + e]] + edn);
        float p = __expf(v - m);
        if (e < CAP2) *(uint*)&al[e] = splat_h2(p);
        ssum += p;
    }
    #pragma unroll
    for (int off = 16; off; off >>= 1) ssum += __shfl_xor(ssum, off);
    float ri = 1.f / (ssum + 1e-16f);

    int c0 = lane32 * 4;
    half2v a01 = {}, a01b = {}, a23 = {}, a23b = {};
    int e = 0;
    for (; e + 4 <= dcap; e += 4) {
        int s0i = ss[e], s1i = ss[e + 1], s2i = ss[e + 2], s3i = ss[e + 3];
        uint2 u0 = *(const uint2*)&h2[(size_t)s0i * OUTC + c0];
        uint2 u1 = *(const uint2*)&h2[(size_t)s1i * OUTC + c0];
        uint2 u2 = *(const uint2*)&h2[(size_t)s2i * OUTC + c0];
        uint2 u3 = *(const uint2*)&h2[(size_t)s3i * OUTC + c0];
        half2v p0 = as_h2(*(const uint*)&al[e]);
        half2v p1 = as_h2(*(const uint*)&al[e + 1]);
        half2v p2 = as_h2(*(const uint*)&al[e + 2]);
        half2v p3 = as_h2(*(const uint*)&al[e + 3]);
        a01  = as_h2(u0.x) * p0 + a01;  a23  = as_h2(u0.y) * p0 + a23;
        a01b = as_h2(u1.x) * p1 + a01b; a23b = as_h2(u1.y) * p1 + a23b;
        a01  = as_h2(u2.x) * p2 + a01;  a23  = as_h2(u2.y) * p2 + a23;
        a01b = as_h2(u3.x) * p3 + a01b; a23b = as_h2(u3.y) * p3 + a23b;
    }
    for (; e < dcap; ++e) {
        int s = ss[e];
        uint2 u = *(const uint2*)&h2[(size_t)s * OUTC + c0];
        half2v p = as_h2(*(const uint*)&al[e]);
        a01 = as_h2(u.x) * p + a01;
        a23 = as_h2(u.y) * p + a23;
    }
    for (; e < deg; ++e) {
        int s = csr_src[beg + e];
        float p = __expf(leaky(esrc[s] + edn) - m);
        half2v ph = as_h2(splat_h2(p));
        uint2 u = *(const uint2*)&h2[(size_t)s * OUTC + c0];
        a01 = as_h2(u.x) * ph + a01;
        a23 = as_h2(u.y) * ph + a23;
    }
    float4 bb = *(const float4*)&b2[c0];
    float4 o;
    o.x = ((float)a01[0] + (float)a01b[0]) * ri + bb.x;
    o.y = ((float)a01[1] + (float)a01b[1]) * ri + bb.y;
    o.z = ((float)a23[0] + (float)a23b[0]) * ri + bb.z;
    o.w = ((float)a23[1] + (float)a23b[1]) * ri + bb.w;
    *(float4*)&out[(size_t)n * OUTC + c0] = o;
}

// ---------------- launch ----------------
extern "C" void kernel_launch(void* const* d_in, const int* in_sizes, int n_in,
                              void* d_out, int out_size, void* d_ws, size_t ws_size,
                              hipStream_t stream) {
    const float* x   = (const float*)d_in[0];
    const int*   ei  = (const int*)  d_in[1];
    const float* W1  = (const float*)d_in[2];
    const float* b1  = (const float*)d_in[3];
    const float* as1 = (const float*)d_in[4];
    const float* ad1 = (const float*)d_in[5];
    const float* W2  = (const float*)d_in[6];
    const float* b2  = (const float*)d_in[7];
    const float* as2 = (const float*)d_in[8];
    const float* ad2 = (const float*)d_in[9];
    float* out = (float*)d_out;

    char* ws = (char*)d_ws;
    size_t off = 0;
    auto alloc = [&](size_t bytes) -> void* {
        void* p = ws + off;
        off = (off + bytes + 255) & ~(size_t)255;
        return p;
    };
    ushort* xh    = (ushort*)alloc((size_t)MPAD * INC * 2);
    ushort* w1t   = (ushort*)alloc((size_t)D1 * INC * 2);
    ushort* w2t   = (ushort*)alloc((size_t)OUTC * D1 * 2);
    ushort* h1h   = (ushort*)alloc((size_t)MPAD * D1 * 2);
    ushort* out1h = (ushort*)alloc((size_t)MPAD * D1 * 2);
    ushort* h2h   = (ushort*)alloc((size_t)MPAD * OUTC * 2);
    float*  es1   = (float*)alloc((size_t)NNODES * NH * 4);
    float*  ed1   = (float*)alloc((size_t)NNODES * NH * 4);
    float*  es2   = (float*)alloc((size_t)NNODES * 4);
    float*  ed2   = (float*)alloc((size_t)NNODES * 4);
    int*    deg   = (int*)alloc((size_t)NNODES * 4);
    int*    rs    = (int*)alloc((size_t)(NNODES + 1) * 4);
    int*    cur   = (int*)alloc((size_t)NNODES * 4);
    int*    csr   = (int*)alloc((size_t)ETOT * 4);

    // CSR build
    hipMemsetAsync(deg, 0, (size_t)NNODES * 4, stream);
    count_deg<<<(ETOT + 255) / 256, 256, 0, stream>>>(ei, deg);
    scan_deg<<<1, 1024, 0, stream>>>(deg, rs);
    hipMemcpyAsync(cur, rs, (size_t)NNODES * 4, hipMemcpyDeviceToDevice, stream);
    scatter_edges<<<(ETOT + 255) / 256, 256, 0, stream>>>(ei, cur, csr);

    // dtype prep
    cast_f16<<<(NNODES * INC / 4 + 255) / 256, 256, 0, stream>>>(x, xh, NNODES * INC / 4);
    cast_wT<<<(INC * D1 + 255) / 256, 256, 0, stream>>>(W1, w1t, INC, D1);
    cast_wT<<<(D1 * OUTC + 255) / 256, 256, 0, stream>>>(W2, w2t, D1, OUTC);

    // layer 1
    gemm_f16<INC><<<dim3(MPAD / 128, D1 / 128), 256, 0, stream>>>(xh, w1t, h1h, NNODES, D1);
    dots1<<<(NNODES * 64 + 255) / 256, 256, 0, stream>>>(h1h, as1, ad1, es1, ed1);
    attn1<<<NNODES / 4, 256, 0, stream>>>(h1h, es1, ed1, rs, csr, b1, out1h);

    // layer 2
    gemm_f16<D1><<<dim3(MPAD / 128, OUTC / 128), 256, 0, stream>>>(out1h, w2t, h2h, NNODES, OUTC);
    dots2<<<(NNODES * 64 + 255) / 256, 256, 0, stream>>>(h2h, as2, ad2, es2, ed2);
    attn2<<<NNODES / 8, 256, 0, stream>>>(h2h, es2, ed2, rs, csr, b2, out);
}